// Round 1
// baseline (862.879 us; speedup 1.0000x reference)
//
#include <hip/hip_runtime.h>

typedef unsigned short u16;
typedef __bf16 bf16x8 __attribute__((ext_vector_type(8)));
typedef unsigned short u16x8 __attribute__((ext_vector_type(8)));
typedef float f32x4 __attribute__((ext_vector_type(4)));

union V8 { u16x8 u; bf16x8 b; };

__device__ __forceinline__ u16 f2bf(float f) {
    unsigned u = __float_as_uint(f);
    u += 0x7fffu + ((u >> 16) & 1u);
    return (u16)(u >> 16);
}
__device__ __forceinline__ float bf2f(u16 h) {
    return __uint_as_float(((unsigned)h) << 16);
}

// block-wide sum for blockDim.x == 256 (4 waves). Returns total to all threads.
__device__ __forceinline__ float block_sum256(float v, float* red) {
#pragma unroll
    for (int mk = 1; mk < 64; mk <<= 1) v += __shfl_xor(v, mk);
    __syncthreads();                  // protect red reuse across calls
    if ((threadIdx.x & 63) == 0) red[threadIdx.x >> 6] = v;
    __syncthreads();
    return red[0] + red[1] + red[2] + red[3];
}

// ---------------------------------------------------------------------------
// cond: cm[b][n] = sum_i silu(c[b][i]) * w_cond[i][n]   (fp32, tiny GEMM)
// grid (6144/256, 8), block 256
__global__ __launch_bounds__(256)
void cond_kernel(const float* __restrict__ c, const float* __restrict__ w,
                 float* __restrict__ cm) {
    __shared__ float sc[1024];
    const int b = blockIdx.y;
    for (int i = threadIdx.x; i < 1024; i += 256) {
        float v = c[b * 1024 + i];
        sc[i] = v / (1.f + expf(-v));
    }
    __syncthreads();
    const int col = blockIdx.x * 256 + threadIdx.x;
    float acc = 0.f;
    for (int i = 0; i < 1024; ++i) acc += sc[i] * w[(size_t)i * 6144 + col];
    cm[b * 6144 + col] = acc;
}

// ---------------------------------------------------------------------------
// LayerNorm (no scale/bias, eps=1e-6, stats fp32, output cast bf16) then
// modulate: out = bf16( bf16(xhat) * scale + shift ).  One block per row.
__global__ __launch_bounds__(256)
void ln_mod_kernel(const float* __restrict__ x, const float* __restrict__ cm,
                   int shift0, int scale0, u16* __restrict__ out) {
    __shared__ float red[8];
    const int row = blockIdx.x, tid = threadIdx.x;
    const int b = row >> 10;
    const float4 v = *(const float4*)(x + (size_t)row * 1024 + tid * 4);
    float s = v.x + v.y + v.z + v.w;
#pragma unroll
    for (int mk = 1; mk < 64; mk <<= 1) s += __shfl_xor(s, mk);
    if ((tid & 63) == 0) red[tid >> 6] = s;
    __syncthreads();
    const float mean = (red[0] + red[1] + red[2] + red[3]) * (1.f / 1024.f);
    const float d0 = v.x - mean, d1 = v.y - mean, d2 = v.z - mean, d3 = v.w - mean;
    float ss = d0 * d0 + d1 * d1 + d2 * d2 + d3 * d3;
#pragma unroll
    for (int mk = 1; mk < 64; mk <<= 1) ss += __shfl_xor(ss, mk);
    if ((tid & 63) == 0) red[4 + (tid >> 6)] = ss;
    __syncthreads();
    const float var = (red[4] + red[5] + red[6] + red[7]) * (1.f / 1024.f);
    const float rs = rsqrtf(var + 1e-6f);
    const float* cmb = cm + b * 6144;
    const int c0 = tid * 4;
    ushort4 ov;
    ov.x = f2bf(bf2f(f2bf(d0 * rs)) * cmb[scale0 + c0 + 0] + cmb[shift0 + c0 + 0]);
    ov.y = f2bf(bf2f(f2bf(d1 * rs)) * cmb[scale0 + c0 + 1] + cmb[shift0 + c0 + 1]);
    ov.z = f2bf(bf2f(f2bf(d2 * rs)) * cmb[scale0 + c0 + 2] + cmb[shift0 + c0 + 2]);
    ov.w = f2bf(bf2f(f2bf(d3 * rs)) * cmb[scale0 + c0 + 3] + cmb[shift0 + c0 + 3]);
    *(ushort4*)(out + (size_t)row * 1024 + c0) = ov;
}

// ---------------------------------------------------------------------------
// fp32 (R,C) -> bf16 transposed (C,R).  block (32,8), grid (C/32, R/32)
__global__ __launch_bounds__(256)
void transpose_cast(const float* __restrict__ in, u16* __restrict__ out,
                    int R, int C) {
    __shared__ float t[32][33];
    const int tx = threadIdx.x, ty = threadIdx.y;
    const int c0 = blockIdx.x * 32, r0 = blockIdx.y * 32;
#pragma unroll
    for (int i = 0; i < 4; ++i)
        t[ty + i * 8][tx] = in[(size_t)(r0 + ty + i * 8) * C + c0 + tx];
    __syncthreads();
#pragma unroll
    for (int i = 0; i < 4; ++i)
        out[(size_t)(c0 + ty + i * 8) * R + r0 + tx] = f2bf(t[tx][ty + i * 8]);
}

// ---------------------------------------------------------------------------
// V slice of kqv -> vT[bh][d][s]  (bf16). block (32,8), grid (32, 2, 128)
__global__ __launch_bounds__(256)
void vtrans_kernel(const u16* __restrict__ kqv, u16* __restrict__ vT) {
    __shared__ u16 t[32][33];
    const int tx = threadIdx.x, ty = threadIdx.y;
    const int s0 = blockIdx.x * 32, d0 = blockIdx.y * 32;
    const int bh = blockIdx.z, b = bh >> 4, h = bh & 15;
#pragma unroll
    for (int i = 0; i < 4; ++i) {
        int s = s0 + ty + i * 8;
        t[ty + i * 8][tx] = kqv[(size_t)(b * 1024 + s) * 3072 + 2048 + h * 64 + d0 + tx];
    }
    __syncthreads();
#pragma unroll
    for (int i = 0; i < 4; ++i) {
        int d = d0 + ty + i * 8;
        vT[((size_t)bh * 64 + d) * 1024 + s0 + tx] = t[tx][ty + i * 8];
    }
}

// ---------------------------------------------------------------------------
// GEMM  C[M][N] = A[M][K] (bf16) @ BT[N][K]^T (bf16), 128x128 tile, BK=32,
// 4 waves each computing 64x64 via 16 x mfma_f32_16x16x32_bf16.
// EPI 0: store bf16 (kqv)
// EPI 1: attn-out: o = resid + gate*acc -> outf; ss_attn/ss_x/ss_x1 -> stats[0..2]
// EPI 2: mlp1: count positives per col, ss->stats[3], gelu(tanh) -> bf16
// EPI 3: mlp2: o = resid + gate*acc -> outf; ss -> stats[4]
template <int EPI>
__global__ __launch_bounds__(256)
void gemm_epi(const u16* __restrict__ A, const u16* __restrict__ BT,
              int M, int N, int K,
              u16* __restrict__ outb, float* __restrict__ outf,
              const float* __restrict__ resid, const float* __restrict__ gatec,
              float* __restrict__ stats, int* __restrict__ counts) {
    __shared__ u16 As[128 * 32];
    __shared__ u16 Bs[128 * 32];
    __shared__ float red[4];
    __shared__ int ccnt[128];

    const int tid = threadIdx.x;
    const int lane = tid & 63;
    const int wave = tid >> 6;
    const int wm = wave & 1, wn = wave >> 1;
    const int quad = lane >> 4, l15 = lane & 15;
    const int tm = blockIdx.y * 128, tn = blockIdx.x * 128;

    const int srow = tid >> 2;        // 0..63
    const int scol = (tid & 3) * 8;   // 0,8,16,24 (bf16 elems; 16B)

    f32x4 acc[4][4];
#pragma unroll
    for (int i = 0; i < 4; ++i)
#pragma unroll
        for (int j = 0; j < 4; ++j) acc[i][j] = (f32x4){0.f, 0.f, 0.f, 0.f};

    for (int k0 = 0; k0 < K; k0 += 32) {
        __syncthreads();
#pragma unroll
        for (int p = 0; p < 2; ++p) {
            const int r = p * 64 + srow;
            *(uint4*)(As + r * 32 + scol) =
                *(const uint4*)(A + (size_t)(tm + r) * K + k0 + scol);
            *(uint4*)(Bs + r * 32 + scol) =
                *(const uint4*)(BT + (size_t)(tn + r) * K + k0 + scol);
        }
        __syncthreads();
        V8 af[4], bfr[4];
#pragma unroll
        for (int i = 0; i < 4; ++i)
            af[i].u = *(const u16x8*)(As + (wm * 64 + i * 16 + l15) * 32 + quad * 8);
#pragma unroll
        for (int j = 0; j < 4; ++j)
            bfr[j].u = *(const u16x8*)(Bs + (wn * 64 + j * 16 + l15) * 32 + quad * 8);
#pragma unroll
        for (int i = 0; i < 4; ++i)
#pragma unroll
            for (int j = 0; j < 4; ++j)
                acc[i][j] = __builtin_amdgcn_mfma_f32_16x16x32_bf16(
                    af[i].b, bfr[j].b, acc[i][j], 0, 0, 0);
    }

    if (EPI == 2) {
        for (int i = tid; i < 128; i += 256) ccnt[i] = 0;
    }
    __syncthreads();

    float s0 = 0.f, s1 = 0.f, s2 = 0.f;
#pragma unroll
    for (int i = 0; i < 4; ++i) {
#pragma unroll
        for (int j = 0; j < 4; ++j) {
#pragma unroll
            for (int r = 0; r < 4; ++r) {
                const int row = tm + wm * 64 + i * 16 + quad * 4 + r;
                const int col = tn + wn * 64 + j * 16 + l15;
                const float v = acc[i][j][r];
                const size_t idx = (size_t)row * N + col;
                if (EPI == 0) {
                    outb[idx] = f2bf(v);
                } else if (EPI == 1) {
                    const int bb = row >> 10;
                    const float g = gatec[bb * 6144 + col];
                    const float xa = g * v;
                    const float xv = resid[idx];
                    const float o = xv + xa;
                    outf[idx] = o;
                    s0 += xa * xa; s1 += xv * xv; s2 += o * o;
                } else if (EPI == 2) {
                    if (v > 0.f) atomicAdd(&ccnt[wn * 64 + j * 16 + l15], 1);
                    s0 += v * v;
                    // tanh-approx gelu: x*e/(e+1), e = exp(2*0.79788456*(x+0.044715x^3))
                    const float a = fminf(0.7978845608028654f * (v + 0.044715f * v * v * v), 40.f);
                    const float e = __expf(2.f * a);
                    outb[idx] = f2bf(v * e / (e + 1.f));
                } else {
                    const int bb = row >> 10;
                    const float g = gatec[bb * 6144 + col];
                    const float xm = g * v;
                    const float o = resid[idx] + xm;
                    outf[idx] = o;
                    s0 += xm * xm;
                }
            }
        }
    }

    if (EPI == 1) {
        float t = block_sum256(s0, red); if (tid == 0) atomicAdd(&stats[0], t);
        t = block_sum256(s1, red);       if (tid == 0) atomicAdd(&stats[1], t);
        t = block_sum256(s2, red);       if (tid == 0) atomicAdd(&stats[2], t);
    } else if (EPI == 2) {
        __syncthreads();
        for (int i = tid; i < 128; i += 256) atomicAdd(&counts[tn + i], ccnt[i]);
        float t = block_sum256(s0, red); if (tid == 0) atomicAdd(&stats[3], t);
    } else if (EPI == 3) {
        float t = block_sum256(s0, red); if (tid == 0) atomicAdd(&stats[4], t);
    }
}

// ---------------------------------------------------------------------------
// Flash attention. grid (16 qtiles, 128 bh), block 256 (4 waves, 16 q rows
// each). kqv rows: [K | Q | V] thirds; vT is [bh][d][s]. Accumulates
// sum(1/l) into stats[5] for info_max_attn_weight.
__global__ __launch_bounds__(256)
void attn_kernel(const u16* __restrict__ kqv, const u16* __restrict__ vT,
                 u16* __restrict__ y, float* __restrict__ stats) {
    __shared__ u16 plds[4 * 16 * 32];
    const int tid = threadIdx.x, lane = tid & 63, w = tid >> 6;
    const int quad = lane >> 4, l15 = lane & 15;
    const int qt = blockIdx.x, bh = blockIdx.y;
    const int b = bh >> 4, h = bh & 15;
    const int qbase = qt * 64 + w * 16;

    const size_t rowQ = ((size_t)(b * 1024 + qbase + l15)) * 3072 + 1024 + h * 64 + quad * 8;
    V8 aq0, aq1;
    aq0.u = *(const u16x8*)(kqv + rowQ);
    aq1.u = *(const u16x8*)(kqv + rowQ + 32);

    float m[4], l[4];
    f32x4 o[4];
#pragma unroll
    for (int r = 0; r < 4; ++r) { m[r] = -__builtin_inff(); l[r] = 0.f; }
#pragma unroll
    for (int j = 0; j < 4; ++j) o[j] = (f32x4){0.f, 0.f, 0.f, 0.f};

    u16* wp = plds + w * 512;
    const size_t vbase = (size_t)bh * 64 * 1024;

    for (int k0 = 0; k0 < 1024; k0 += 32) {
        f32x4 sc0 = (f32x4){0.f, 0.f, 0.f, 0.f};
        f32x4 sc1 = (f32x4){0.f, 0.f, 0.f, 0.f};
        {
            const size_t rowK0 = ((size_t)(b * 1024 + k0 + l15)) * 3072 + h * 64 + quad * 8;
            V8 kf;
            kf.u = *(const u16x8*)(kqv + rowK0);
            sc0 = __builtin_amdgcn_mfma_f32_16x16x32_bf16(aq0.b, kf.b, sc0, 0, 0, 0);
            kf.u = *(const u16x8*)(kqv + rowK0 + 32);
            sc0 = __builtin_amdgcn_mfma_f32_16x16x32_bf16(aq1.b, kf.b, sc0, 0, 0, 0);
            const size_t rowK1 = rowK0 + (size_t)16 * 3072;
            kf.u = *(const u16x8*)(kqv + rowK1);
            sc1 = __builtin_amdgcn_mfma_f32_16x16x32_bf16(aq0.b, kf.b, sc1, 0, 0, 0);
            kf.u = *(const u16x8*)(kqv + rowK1 + 32);
            sc1 = __builtin_amdgcn_mfma_f32_16x16x32_bf16(aq1.b, kf.b, sc1, 0, 0, 0);
        }
        __syncthreads();   // guards WAR on plds vs previous iteration's reads
#pragma unroll
        for (int r = 0; r < 4; ++r) {
            const float l0 = sc0[r] * 0.125f, l1 = sc1[r] * 0.125f;
            float tmax = fmaxf(l0, l1);
#pragma unroll
            for (int mk = 1; mk < 16; mk <<= 1) tmax = fmaxf(tmax, __shfl_xor(tmax, mk));
            const float mn = fmaxf(m[r], tmax);
            const float alpha = __expf(m[r] - mn);
            const float p0 = __expf(l0 - mn), p1 = __expf(l1 - mn);
            float rs = p0 + p1;
#pragma unroll
            for (int mk = 1; mk < 16; mk <<= 1) rs += __shfl_xor(rs, mk);
            l[r] = l[r] * alpha + rs;
            m[r] = mn;
#pragma unroll
            for (int j = 0; j < 4; ++j) o[j][r] *= alpha;
            wp[(quad * 4 + r) * 32 + l15] = f2bf(p0);
            wp[(quad * 4 + r) * 32 + 16 + l15] = f2bf(p1);
        }
        __syncthreads();   // P writes -> A-fragment reads
        V8 pa;
        pa.u = *(const u16x8*)(wp + l15 * 32 + quad * 8);
#pragma unroll
        for (int dt = 0; dt < 4; ++dt) {
            V8 vf;
            vf.u = *(const u16x8*)(vT + vbase + (size_t)(dt * 16 + l15) * 1024 + k0 + quad * 8);
            o[dt] = __builtin_amdgcn_mfma_f32_16x16x32_bf16(pa.b, vf.b, o[dt], 0, 0, 0);
        }
    }

    float invl[4];
#pragma unroll
    for (int r = 0; r < 4; ++r) invl[r] = 1.f / l[r];
#pragma unroll
    for (int dt = 0; dt < 4; ++dt)
#pragma unroll
        for (int r = 0; r < 4; ++r) {
            const size_t orow = (size_t)(b * 1024 + qbase + quad * 4 + r);
            y[orow * 1024 + h * 64 + dt * 16 + l15] = f2bf(o[dt][r] * invl[r]);
        }

    // sum of 1/l over this wave's 16 rows (value replicated across 16 lanes
    // of each quad group -> take l15==0 only), then wave butterfly + atomic.
    float sv = (l15 == 0) ? (invl[0] + invl[1] + invl[2] + invl[3]) : 0.f;
#pragma unroll
    for (int mk = 1; mk < 64; mk <<= 1) sv += __shfl_xor(sv, mk);
    if (lane == 0) atomicAdd(&stats[5], sv);
}

// ---------------------------------------------------------------------------
__global__ __launch_bounds__(256)
void finalize_kernel(const int* __restrict__ counts, const float* __restrict__ stats,
                     float* __restrict__ out7) {
    __shared__ float red[4];
    float d = 0.f, z = 0.f, pp = 0.f;
    for (int i = threadIdx.x; i < 4096; i += 256) {
        const int c = counts[i];
        const float frac = (float)c * (1.f / 8192.f);
        d += fabsf(frac - 0.5f);
        z += (c == 0) ? 1.f : 0.f;
        pp += (c == 8192) ? 1.f : 0.f;
    }
    d = block_sum256(d, red);
    z = block_sum256(z, red);
    pp = block_sum256(pp, red);
    if (threadIdx.x == 0) {
        out7[0] = d * (1.f / 4096.f);                 // info_relu_diff
        out7[1] = z * (1.f / 4096.f);                 // info_relu_zero
        out7[2] = pp * (1.f / 4096.f);                // info_relu_positive
        out7[3] = stats[5] * (1.f / 131072.f);        // info_max_attn_weight
        out7[4] = sqrtf(stats[0] / stats[1]);         // info_attn_norm_ratio
        out7[5] = sqrtf(stats[4] / stats[2]);         // info_mlp_norm_ratio
        out7[6] = sqrtf(stats[3] / (8192.f * 4096.f)); // info_relu_norm
    }
}

// ---------------------------------------------------------------------------
extern "C" void kernel_launch(void* const* d_in, const int* in_sizes, int n_in,
                              void* d_out, int out_size, void* d_ws, size_t ws_size,
                              hipStream_t stream) {
    const float* x      = (const float*)d_in[0];
    const float* c      = (const float*)d_in[1];
    const float* w_cond = (const float*)d_in[2];
    const float* w_qkv  = (const float*)d_in[3];
    const float* w_attn = (const float*)d_in[4];
    const float* w_mlp1 = (const float*)d_in[5];
    const float* w_mlp2 = (const float*)d_in[6];
    float* out = (float*)d_out;

    char* base = (char*)d_ws;
    size_t off = 0;
    auto alloc = [&](size_t n) { void* r = base + off; off += (n + 255) & ~(size_t)255; return r; };
    float* stats   = (float*)alloc(64);                       // [0..5] accum slots
    int*   counts  = (int*)alloc(4096 * 4);
    float* cm      = (float*)alloc((size_t)8 * 6144 * 4);
    u16*   x_mod   = (u16*)alloc((size_t)8192 * 1024 * 2);    // reused as x_mod2
    u16*   kqv     = (u16*)alloc((size_t)8192 * 3072 * 2);    // reused (with vT) as h_act
    u16*   vT      = (u16*)alloc((size_t)128 * 64 * 1024 * 2);
    u16*   y       = (u16*)alloc((size_t)8192 * 1024 * 2);
    float* x1      = (float*)alloc((size_t)8192 * 1024 * 4);
    u16*   wt_qkv  = (u16*)alloc((size_t)3072 * 1024 * 2);
    u16*   wt_attn = (u16*)alloc((size_t)1024 * 1024 * 2);
    u16*   wt_mlp1 = (u16*)alloc((size_t)4096 * 1024 * 2);
    u16*   wt_mlp2 = (u16*)alloc((size_t)1024 * 4096 * 2);
    u16*   h_act   = kqv;      // 64 MB spans kqv(48MB)+vT(16MB), both dead by then
    u16*   x_mod2  = x_mod;
    (void)vT; (void)ws_size; (void)n_in; (void)in_sizes; (void)out_size;

    // zero stats + counts (ws is poisoned 0xAA before every call)
    hipMemsetAsync(d_ws, 0, 256 + 4096 * 4, stream);

    dim3 tb(32, 8);
    // weight transpose+cast: in (R,C) fp32 -> out (C,R) bf16
    transpose_cast<<<dim3(3072 / 32, 1024 / 32), tb, 0, stream>>>(w_qkv,  wt_qkv,  1024, 3072);
    transpose_cast<<<dim3(1024 / 32, 1024 / 32), tb, 0, stream>>>(w_attn, wt_attn, 1024, 1024);
    transpose_cast<<<dim3(4096 / 32, 1024 / 32), tb, 0, stream>>>(w_mlp1, wt_mlp1, 1024, 4096);
    transpose_cast<<<dim3(1024 / 32, 4096 / 32), tb, 0, stream>>>(w_mlp2, wt_mlp2, 4096, 1024);

    cond_kernel<<<dim3(24, 8), 256, 0, stream>>>(c, w_cond, cm);

    // LN + modulate (shift_msa=cm[:,0:H], scale_msa=cm[:,H:2H])
    ln_mod_kernel<<<8192, 256, 0, stream>>>(x, cm, 0, 1024, x_mod);

    // kqv = x_mod @ w_qkv  -> bf16 [8192][3072] (order: K | Q | V)
    gemm_epi<0><<<dim3(3072 / 128, 8192 / 128), 256, 0, stream>>>(
        x_mod, wt_qkv, 8192, 3072, 1024, kqv, nullptr, nullptr, nullptr, stats, nullptr);

    vtrans_kernel<<<dim3(32, 2, 128), tb, 0, stream>>>(kqv, vT);

    attn_kernel<<<dim3(16, 128), 256, 0, stream>>>(kqv, vT, y, stats);

    // x1 = x + gate_msa * (y @ w_attn_out); stats: ss_attn, ss_x, ss_x1
    gemm_epi<1><<<dim3(1024 / 128, 8192 / 128), 256, 0, stream>>>(
        y, wt_attn, 8192, 1024, 1024, nullptr, x1, x, cm + 2 * 1024, stats, nullptr);

    // LN + modulate (shift_mlp=cm[:,3H:4H], scale_mlp=cm[:,4H:5H])
    ln_mod_kernel<<<8192, 256, 0, stream>>>(x1, cm, 3 * 1024, 4 * 1024, x_mod2);

    // x_mlp = x_mod2 @ w_mlp1; counts, ss_mlp1, gelu -> h_act bf16
    gemm_epi<2><<<dim3(4096 / 128, 8192 / 128), 256, 0, stream>>>(
        x_mod2, wt_mlp1, 8192, 4096, 1024, h_act, nullptr, nullptr, nullptr, stats, counts);

    // out = x1 + gate_mlp * (h_act @ w_mlp2); ss_mlp2
    gemm_epi<3><<<dim3(1024 / 128, 8192 / 128), 256, 0, stream>>>(
        h_act, wt_mlp2, 8192, 1024, 4096, nullptr, out, x1, cm + 5 * 1024, stats, nullptr);

    finalize_kernel<<<1, 256, 0, stream>>>(counts, stats, out + (size_t)8192 * 1024);
}

// Round 2
// 714.365 us; speedup vs baseline: 1.2079x; 1.2079x over previous
//
#include <hip/hip_runtime.h>

typedef unsigned short u16;
typedef __bf16 bf16x8 __attribute__((ext_vector_type(8)));
typedef unsigned short u16x8 __attribute__((ext_vector_type(8)));
typedef float f32x4 __attribute__((ext_vector_type(4)));

union V8 { u16x8 u; bf16x8 b; };

__device__ __forceinline__ u16 f2bf(float f) {
    unsigned u = __float_as_uint(f);
    u += 0x7fffu + ((u >> 16) & 1u);
    return (u16)(u >> 16);
}
__device__ __forceinline__ float bf2f(u16 h) {
    return __uint_as_float(((unsigned)h) << 16);
}

// async global->LDS, 16B per lane. LDS dest = wave-uniform base + lane*16.
__device__ __forceinline__ void gld16(const void* g, void* l) {
    __builtin_amdgcn_global_load_lds(
        (const __attribute__((address_space(1))) void*)g,
        (__attribute__((address_space(3))) void*)l, 16, 0, 0);
}

// block-wide sum for blockDim.x == 256 (4 waves). Returns total to all threads.
__device__ __forceinline__ float block_sum256(float v, float* red) {
#pragma unroll
    for (int mk = 1; mk < 64; mk <<= 1) v += __shfl_xor(v, mk);
    __syncthreads();                  // protect red reuse across calls
    if ((threadIdx.x & 63) == 0) red[threadIdx.x >> 6] = v;
    __syncthreads();
    return red[0] + red[1] + red[2] + red[3];
}

// ---------------------------------------------------------------------------
// cond: cm[b][n] = sum_i silu(c[b][i]) * w_cond[i][n]   (fp32, tiny GEMM)
__global__ __launch_bounds__(256)
void cond_kernel(const float* __restrict__ c, const float* __restrict__ w,
                 float* __restrict__ cm) {
    __shared__ float sc[1024];
    const int b = blockIdx.y;
    for (int i = threadIdx.x; i < 1024; i += 256) {
        float v = c[b * 1024 + i];
        sc[i] = v / (1.f + expf(-v));
    }
    __syncthreads();
    const int col = blockIdx.x * 256 + threadIdx.x;
    float acc = 0.f;
    for (int i = 0; i < 1024; ++i) acc += sc[i] * w[(size_t)i * 6144 + col];
    cm[b * 6144 + col] = acc;
}

// ---------------------------------------------------------------------------
// LayerNorm (stats fp32, output cast bf16) then modulate (bf16 semantics).
__global__ __launch_bounds__(256)
void ln_mod_kernel(const float* __restrict__ x, const float* __restrict__ cm,
                   int shift0, int scale0, u16* __restrict__ out) {
    __shared__ float red[8];
    const int row = blockIdx.x, tid = threadIdx.x;
    const int b = row >> 10;
    const float4 v = *(const float4*)(x + (size_t)row * 1024 + tid * 4);
    float s = v.x + v.y + v.z + v.w;
#pragma unroll
    for (int mk = 1; mk < 64; mk <<= 1) s += __shfl_xor(s, mk);
    if ((tid & 63) == 0) red[tid >> 6] = s;
    __syncthreads();
    const float mean = (red[0] + red[1] + red[2] + red[3]) * (1.f / 1024.f);
    const float d0 = v.x - mean, d1 = v.y - mean, d2 = v.z - mean, d3 = v.w - mean;
    float ss = d0 * d0 + d1 * d1 + d2 * d2 + d3 * d3;
#pragma unroll
    for (int mk = 1; mk < 64; mk <<= 1) ss += __shfl_xor(ss, mk);
    if ((tid & 63) == 0) red[4 + (tid >> 6)] = ss;
    __syncthreads();
    const float var = (red[4] + red[5] + red[6] + red[7]) * (1.f / 1024.f);
    const float rs = rsqrtf(var + 1e-6f);
    const float* cmb = cm + b * 6144;
    const int c0 = tid * 4;
    ushort4 ov;
    ov.x = f2bf(bf2f(f2bf(d0 * rs)) * cmb[scale0 + c0 + 0] + cmb[shift0 + c0 + 0]);
    ov.y = f2bf(bf2f(f2bf(d1 * rs)) * cmb[scale0 + c0 + 1] + cmb[shift0 + c0 + 1]);
    ov.z = f2bf(bf2f(f2bf(d2 * rs)) * cmb[scale0 + c0 + 2] + cmb[shift0 + c0 + 2]);
    ov.w = f2bf(bf2f(f2bf(d3 * rs)) * cmb[scale0 + c0 + 3] + cmb[shift0 + c0 + 3]);
    *(ushort4*)(out + (size_t)row * 1024 + c0) = ov;
}

// ---------------------------------------------------------------------------
// fp32 (R,C) -> bf16 transposed (C,R).  block (32,8), grid (C/32, R/32)
__global__ __launch_bounds__(256)
void transpose_cast(const float* __restrict__ in, u16* __restrict__ out,
                    int R, int C) {
    __shared__ float t[32][33];
    const int tx = threadIdx.x, ty = threadIdx.y;
    const int c0 = blockIdx.x * 32, r0 = blockIdx.y * 32;
#pragma unroll
    for (int i = 0; i < 4; ++i)
        t[ty + i * 8][tx] = in[(size_t)(r0 + ty + i * 8) * C + c0 + tx];
    __syncthreads();
#pragma unroll
    for (int i = 0; i < 4; ++i)
        out[(size_t)(c0 + ty + i * 8) * R + r0 + tx] = f2bf(t[tx][ty + i * 8]);
}

// ---------------------------------------------------------------------------
// V slice of kqv -> vT[bh][d][s]  (bf16). block (32,8), grid (32, 2, 128)
__global__ __launch_bounds__(256)
void vtrans_kernel(const u16* __restrict__ kqv, u16* __restrict__ vT) {
    __shared__ u16 t[32][33];
    const int tx = threadIdx.x, ty = threadIdx.y;
    const int s0 = blockIdx.x * 32, d0 = blockIdx.y * 32;
    const int bh = blockIdx.z, b = bh >> 4, h = bh & 15;
#pragma unroll
    for (int i = 0; i < 4; ++i) {
        int s = s0 + ty + i * 8;
        t[ty + i * 8][tx] = kqv[(size_t)(b * 1024 + s) * 3072 + 2048 + h * 64 + d0 + tx];
    }
    __syncthreads();
#pragma unroll
    for (int i = 0; i < 4; ++i) {
        int d = d0 + ty + i * 8;
        vT[((size_t)bh * 64 + d) * 1024 + s0 + tx] = t[tx][ty + i * 8];
    }
}

// ---------------------------------------------------------------------------
// GEMM  C[M][N] = A[M][K] (bf16) @ BT[N][K]^T (bf16), 128x128 tile, BK=32,
// global_load_lds (width 16) staging (m97 pattern), 4 waves x 64x64.
// EPI 0: store bf16 (kqv)
// EPI 1: attn-out: o = resid + gate*acc -> outf; ss_attn/ss_x/ss_x1
// EPI 2: mlp1: positives per col, ss, gelu -> bf16
// EPI 3: mlp2: o = resid + gate*acc -> outf; ss
template <int EPI>
__global__ __launch_bounds__(256)
void gemm_epi(const u16* __restrict__ A, const u16* __restrict__ BT,
              int M, int N, int K,
              u16* __restrict__ outb, float* __restrict__ outf,
              const float* __restrict__ resid, const float* __restrict__ gatec,
              float* __restrict__ stats, int* __restrict__ counts) {
    __shared__ u16 As[128 * 32];
    __shared__ u16 Bs[128 * 32];
    __shared__ float red[4];
    __shared__ int ccnt[128];

    const int tid = threadIdx.x;
    const int lane = tid & 63;
    const int wave = tid >> 6;
    const int wm = wave & 1, wn = wave >> 1;
    const int quad = lane >> 4, l15 = lane & 15;
    const int tm = blockIdx.y * 128, tn = blockIdx.x * 128;

    const int srow = tid >> 2;        // 0..63
    const int scol = (tid & 3) * 8;   // 0,8,16,24 (bf16 elems; 16B)

    f32x4 acc[4][4];
#pragma unroll
    for (int i = 0; i < 4; ++i)
#pragma unroll
        for (int j = 0; j < 4; ++j) acc[i][j] = (f32x4){0.f, 0.f, 0.f, 0.f};

    for (int k0 = 0; k0 < K; k0 += 32) {
        __syncthreads();
        // LDS byte addr for chunk p = p*4096 + tid*16  -> lane-linear, so
        // wave-uniform base = p*4096 + wave*1024 bytes (= p*2048 + wave*512 u16)
#pragma unroll
        for (int p = 0; p < 2; ++p) {
            const int r = p * 64 + srow;
            gld16(A + (size_t)(tm + r) * K + k0 + scol, As + p * 2048 + wave * 512);
            gld16(BT + (size_t)(tn + r) * K + k0 + scol, Bs + p * 2048 + wave * 512);
        }
        __syncthreads();
        V8 af[4], bfr[4];
#pragma unroll
        for (int i = 0; i < 4; ++i)
            af[i].u = *(const u16x8*)(As + (wm * 64 + i * 16 + l15) * 32 + quad * 8);
#pragma unroll
        for (int j = 0; j < 4; ++j)
            bfr[j].u = *(const u16x8*)(Bs + (wn * 64 + j * 16 + l15) * 32 + quad * 8);
#pragma unroll
        for (int i = 0; i < 4; ++i)
#pragma unroll
            for (int j = 0; j < 4; ++j)
                acc[i][j] = __builtin_amdgcn_mfma_f32_16x16x32_bf16(
                    af[i].b, bfr[j].b, acc[i][j], 0, 0, 0);
    }

    if (EPI == 2) {
        for (int i = tid; i < 128; i += 256) ccnt[i] = 0;
    }
    __syncthreads();

    float s0 = 0.f, s1 = 0.f, s2 = 0.f;
#pragma unroll
    for (int i = 0; i < 4; ++i) {
#pragma unroll
        for (int j = 0; j < 4; ++j) {
#pragma unroll
            for (int r = 0; r < 4; ++r) {
                const int row = tm + wm * 64 + i * 16 + quad * 4 + r;
                const int col = tn + wn * 64 + j * 16 + l15;
                const float v = acc[i][j][r];
                const size_t idx = (size_t)row * N + col;
                if (EPI == 0) {
                    outb[idx] = f2bf(v);
                } else if (EPI == 1) {
                    const int bb = row >> 10;
                    const float g = gatec[bb * 6144 + col];
                    const float xa = g * v;
                    const float xv = resid[idx];
                    const float o = xv + xa;
                    outf[idx] = o;
                    s0 += xa * xa; s1 += xv * xv; s2 += o * o;
                } else if (EPI == 2) {
                    if (v > 0.f) atomicAdd(&ccnt[wn * 64 + j * 16 + l15], 1);
                    s0 += v * v;
                    const float a = fminf(0.7978845608028654f * (v + 0.044715f * v * v * v), 40.f);
                    const float e = __expf(2.f * a);
                    outb[idx] = f2bf(v * e / (e + 1.f));
                } else {
                    const int bb = row >> 10;
                    const float g = gatec[bb * 6144 + col];
                    const float xm = g * v;
                    const float o = resid[idx] + xm;
                    outf[idx] = o;
                    s0 += xm * xm;
                }
            }
        }
    }

    if (EPI == 1) {
        float t = block_sum256(s0, red); if (tid == 0) atomicAdd(&stats[0], t);
        t = block_sum256(s1, red);       if (tid == 0) atomicAdd(&stats[1], t);
        t = block_sum256(s2, red);       if (tid == 0) atomicAdd(&stats[2], t);
    } else if (EPI == 2) {
        __syncthreads();
        for (int i = tid; i < 128; i += 256) atomicAdd(&counts[tn + i], ccnt[i]);
        float t = block_sum256(s0, red); if (tid == 0) atomicAdd(&stats[3], t);
    } else if (EPI == 3) {
        float t = block_sum256(s0, red); if (tid == 0) atomicAdd(&stats[4], t);
    }
}

// ---------------------------------------------------------------------------
// Flash attention, BK=128. grid (16 qtiles, 128 bh), block 256 (4 waves,
// 16 q rows each). K/V tiles staged via global_load_lds with XOR swizzle
// folded into the global source index (LDS write is lane-linear by HW).
//   Ks[row][col8'] = K[row][col8' ^ (row&7)]   (col8 = 16B chunk of dh)
//   Vs[d][col8']   = vT[d][col8' ^ (d&15)]     (col8 = 16B chunk of 128 keys)
// P round-trip is wave-private -> no barrier between P write and PV read.
__global__ __launch_bounds__(256)
void attn_kernel(const u16* __restrict__ kqv, const u16* __restrict__ vT,
                 u16* __restrict__ y, float* __restrict__ stats) {
    __shared__ u16 Ks[128 * 64];
    __shared__ u16 Vs[64 * 128];
    __shared__ u16 P[4 * 16 * 136];      // per-wave [16][136] (pad 8)
    const int tid = threadIdx.x, lane = tid & 63, w = tid >> 6;
    const int quad = lane >> 4, l15 = lane & 15;
    const int qt = blockIdx.x, bh = blockIdx.y;
    const int b = bh >> 4, h = bh & 15;
    const int qbase = qt * 64 + w * 16;

    const size_t rowQ = ((size_t)(b * 1024 + qbase + l15)) * 3072 + 1024 + h * 64 + quad * 8;
    V8 aq0, aq1;
    aq0.u = *(const u16x8*)(kqv + rowQ);
    aq1.u = *(const u16x8*)(kqv + rowQ + 32);

    float m[4], l[4];
    f32x4 o[4];
#pragma unroll
    for (int r = 0; r < 4; ++r) { m[r] = -__builtin_inff(); l[r] = 0.f; }
#pragma unroll
    for (int dt = 0; dt < 4; ++dt) o[dt] = (f32x4){0.f, 0.f, 0.f, 0.f};

    u16* wp = P + w * (16 * 136);
    const size_t kbase = (size_t)(b * 1024) * 3072 + h * 64;
    const size_t vbase = (size_t)bh * 65536;

    for (int k0 = 0; k0 < 1024; k0 += 128) {
        __syncthreads();   // all waves done reading previous Ks/Vs
#pragma unroll
        for (int i = 0; i < 4; ++i) {
            const int c = i * 256 + tid;            // 16B chunk index
            {   // K tile: 128 rows x 8 chunks
                const int row = c >> 3, col8 = (c & 7) ^ (row & 7);
                gld16(kqv + kbase + (size_t)(k0 + row) * 3072 + col8 * 8,
                      Ks + (i * 256 + w * 64) * 8);
            }
            {   // V tile: 64 rows x 16 chunks
                const int d = c >> 4, col8 = (c & 15) ^ (d & 15);
                gld16(vT + vbase + (size_t)d * 1024 + k0 + col8 * 8,
                      Vs + (i * 256 + w * 64) * 8);
            }
        }
        __syncthreads();   // loads visible

        // ---- QK^T: 16 q rows x 128 keys ----
        f32x4 sc[8];
#pragma unroll
        for (int jt = 0; jt < 8; ++jt) {
            sc[jt] = (f32x4){0.f, 0.f, 0.f, 0.f};
            const int row = jt * 16 + l15;
            V8 kf0, kf1;
            kf0.u = *(const u16x8*)(Ks + row * 64 + ((quad ^ (l15 & 7)) * 8));
            kf1.u = *(const u16x8*)(Ks + row * 64 + (((quad + 4) ^ (l15 & 7)) * 8));
            sc[jt] = __builtin_amdgcn_mfma_f32_16x16x32_bf16(aq0.b, kf0.b, sc[jt], 0, 0, 0);
            sc[jt] = __builtin_amdgcn_mfma_f32_16x16x32_bf16(aq1.b, kf1.b, sc[jt], 0, 0, 0);
        }

        // ---- online softmax over the 128 new scores per row ----
#pragma unroll
        for (int r = 0; r < 4; ++r) {
            float mx = sc[0][r];
#pragma unroll
            for (int jt = 1; jt < 8; ++jt) mx = fmaxf(mx, sc[jt][r]);
            mx *= 0.125f;
#pragma unroll
            for (int mk = 1; mk < 16; mk <<= 1) mx = fmaxf(mx, __shfl_xor(mx, mk));
            const float mn = fmaxf(m[r], mx);
            const float alpha = __expf(m[r] - mn);
            float ps = 0.f;
#pragma unroll
            for (int jt = 0; jt < 8; ++jt) {
                const float p = __expf(sc[jt][r] * 0.125f - mn);
                ps += p;
                wp[(quad * 4 + r) * 136 + jt * 16 + l15] = f2bf(p);
            }
#pragma unroll
            for (int mk = 1; mk < 16; mk <<= 1) ps += __shfl_xor(ps, mk);
            l[r] = l[r] * alpha + ps;
            m[r] = mn;
#pragma unroll
            for (int dt = 0; dt < 4; ++dt) o[dt][r] *= alpha;
        }

        // ---- PV: wave-private P, no barrier needed ----
#pragma unroll
        for (int j = 0; j < 4; ++j) {
            V8 pa;
            pa.u = *(const u16x8*)(wp + l15 * 136 + j * 32 + quad * 8);
#pragma unroll
            for (int dt = 0; dt < 4; ++dt) {
                const int d = dt * 16 + l15;
                V8 vf;
                vf.u = *(const u16x8*)(Vs + d * 128 + (((j * 4 + quad) ^ l15) * 8));
                o[dt] = __builtin_amdgcn_mfma_f32_16x16x32_bf16(pa.b, vf.b, o[dt], 0, 0, 0);
            }
        }
    }

    float invl[4];
#pragma unroll
    for (int r = 0; r < 4; ++r) invl[r] = 1.f / l[r];
#pragma unroll
    for (int dt = 0; dt < 4; ++dt)
#pragma unroll
        for (int r = 0; r < 4; ++r) {
            const size_t orow = (size_t)(b * 1024 + qbase + quad * 4 + r);
            y[orow * 1024 + h * 64 + dt * 16 + l15] = f2bf(o[dt][r] * invl[r]);
        }

    float sv = (l15 == 0) ? (invl[0] + invl[1] + invl[2] + invl[3]) : 0.f;
#pragma unroll
    for (int mk = 1; mk < 64; mk <<= 1) sv += __shfl_xor(sv, mk);
    if (lane == 0) atomicAdd(&stats[5], sv);
}

// ---------------------------------------------------------------------------
__global__ __launch_bounds__(256)
void finalize_kernel(const int* __restrict__ counts, const float* __restrict__ stats,
                     float* __restrict__ out7) {
    __shared__ float red[4];
    float d = 0.f, z = 0.f, pp = 0.f;
    for (int i = threadIdx.x; i < 4096; i += 256) {
        const int c = counts[i];
        const float frac = (float)c * (1.f / 8192.f);
        d += fabsf(frac - 0.5f);
        z += (c == 0) ? 1.f : 0.f;
        pp += (c == 8192) ? 1.f : 0.f;
    }
    d = block_sum256(d, red);
    z = block_sum256(z, red);
    pp = block_sum256(pp, red);
    if (threadIdx.x == 0) {
        out7[0] = d * (1.f / 4096.f);                 // info_relu_diff
        out7[1] = z * (1.f / 4096.f);                 // info_relu_zero
        out7[2] = pp * (1.f / 4096.f);                // info_relu_positive
        out7[3] = stats[5] * (1.f / 131072.f);        // info_max_attn_weight
        out7[4] = sqrtf(stats[0] / stats[1]);         // info_attn_norm_ratio
        out7[5] = sqrtf(stats[4] / stats[2]);         // info_mlp_norm_ratio
        out7[6] = sqrtf(stats[3] / (8192.f * 4096.f)); // info_relu_norm
    }
}

// ---------------------------------------------------------------------------
extern "C" void kernel_launch(void* const* d_in, const int* in_sizes, int n_in,
                              void* d_out, int out_size, void* d_ws, size_t ws_size,
                              hipStream_t stream) {
    const float* x      = (const float*)d_in[0];
    const float* c      = (const float*)d_in[1];
    const float* w_cond = (const float*)d_in[2];
    const float* w_qkv  = (const float*)d_in[3];
    const float* w_attn = (const float*)d_in[4];
    const float* w_mlp1 = (const float*)d_in[5];
    const float* w_mlp2 = (const float*)d_in[6];
    float* out = (float*)d_out;

    char* base = (char*)d_ws;
    size_t off = 0;
    auto alloc = [&](size_t n) { void* r = base + off; off += (n + 255) & ~(size_t)255; return r; };
    float* stats   = (float*)alloc(64);                       // [0..5] accum slots
    int*   counts  = (int*)alloc(4096 * 4);
    float* cm      = (float*)alloc((size_t)8 * 6144 * 4);
    u16*   x_mod   = (u16*)alloc((size_t)8192 * 1024 * 2);    // reused as x_mod2
    u16*   kqv     = (u16*)alloc((size_t)8192 * 3072 * 2);    // reused (with vT) as h_act
    u16*   vT      = (u16*)alloc((size_t)128 * 64 * 1024 * 2);
    u16*   y       = (u16*)alloc((size_t)8192 * 1024 * 2);
    float* x1      = (float*)alloc((size_t)8192 * 1024 * 4);
    u16*   wt_qkv  = (u16*)alloc((size_t)3072 * 1024 * 2);
    u16*   wt_attn = (u16*)alloc((size_t)1024 * 1024 * 2);
    u16*   wt_mlp1 = (u16*)alloc((size_t)4096 * 1024 * 2);
    u16*   wt_mlp2 = (u16*)alloc((size_t)1024 * 4096 * 2);
    u16*   h_act   = kqv;      // 64 MB spans kqv(48MB)+vT(16MB), both dead by then
    u16*   x_mod2  = x_mod;
    (void)vT; (void)ws_size; (void)n_in; (void)in_sizes; (void)out_size;

    hipMemsetAsync(d_ws, 0, 256 + 4096 * 4, stream);

    dim3 tb(32, 8);
    transpose_cast<<<dim3(3072 / 32, 1024 / 32), tb, 0, stream>>>(w_qkv,  wt_qkv,  1024, 3072);
    transpose_cast<<<dim3(1024 / 32, 1024 / 32), tb, 0, stream>>>(w_attn, wt_attn, 1024, 1024);
    transpose_cast<<<dim3(4096 / 32, 1024 / 32), tb, 0, stream>>>(w_mlp1, wt_mlp1, 1024, 4096);
    transpose_cast<<<dim3(1024 / 32, 4096 / 32), tb, 0, stream>>>(w_mlp2, wt_mlp2, 4096, 1024);

    cond_kernel<<<dim3(24, 8), 256, 0, stream>>>(c, w_cond, cm);

    ln_mod_kernel<<<8192, 256, 0, stream>>>(x, cm, 0, 1024, x_mod);

    gemm_epi<0><<<dim3(3072 / 128, 8192 / 128), 256, 0, stream>>>(
        x_mod, wt_qkv, 8192, 3072, 1024, kqv, nullptr, nullptr, nullptr, stats, nullptr);

    vtrans_kernel<<<dim3(32, 2, 128), tb, 0, stream>>>(kqv, vT);

    attn_kernel<<<dim3(16, 128), 256, 0, stream>>>(kqv, vT, y, stats);

    gemm_epi<1><<<dim3(1024 / 128, 8192 / 128), 256, 0, stream>>>(
        y, wt_attn, 8192, 1024, 1024, nullptr, x1, x, cm + 2 * 1024, stats, nullptr);

    ln_mod_kernel<<<8192, 256, 0, stream>>>(x1, cm, 3 * 1024, 4 * 1024, x_mod2);

    gemm_epi<2><<<dim3(4096 / 128, 8192 / 128), 256, 0, stream>>>(
        x_mod2, wt_mlp1, 8192, 4096, 1024, h_act, nullptr, nullptr, nullptr, stats, counts);

    gemm_epi<3><<<dim3(1024 / 128, 8192 / 128), 256, 0, stream>>>(
        h_act, wt_mlp2, 8192, 1024, 4096, nullptr, out, x1, cm + 5 * 1024, stats, nullptr);

    finalize_kernel<<<1, 256, 0, stream>>>(counts, stats, out + (size_t)8192 * 1024);
}

// Round 3
// 653.040 us; speedup vs baseline: 1.3213x; 1.0939x over previous
//
#include <hip/hip_runtime.h>

typedef unsigned short u16;
typedef __bf16 bf16x8 __attribute__((ext_vector_type(8)));
typedef unsigned short u16x8 __attribute__((ext_vector_type(8)));
typedef float f32x4 __attribute__((ext_vector_type(4)));

union V8 { u16x8 u; bf16x8 b; };

__device__ __forceinline__ u16 f2bf(float f) {
    unsigned u = __float_as_uint(f);
    u += 0x7fffu + ((u >> 16) & 1u);
    return (u16)(u >> 16);
}
__device__ __forceinline__ float bf2f(u16 h) {
    return __uint_as_float(((unsigned)h) << 16);
}

// async global->LDS, 16B per lane. LDS dest = wave-uniform base + lane*16.
__device__ __forceinline__ void gld16(const void* g, void* l) {
    __builtin_amdgcn_global_load_lds(
        (const __attribute__((address_space(1))) void*)g,
        (__attribute__((address_space(3))) void*)l, 16, 0, 0);
}

// block-wide sum for blockDim.x == 256 (4 waves). Returns total to all threads.
__device__ __forceinline__ float block_sum256(float v, float* red) {
#pragma unroll
    for (int mk = 1; mk < 64; mk <<= 1) v += __shfl_xor(v, mk);
    __syncthreads();                  // protect red reuse across calls
    if ((threadIdx.x & 63) == 0) red[threadIdx.x >> 6] = v;
    __syncthreads();
    return red[0] + red[1] + red[2] + red[3];
}

// ---------------------------------------------------------------------------
// cond: cm[b][n] = sum_i silu(c[b][i]) * w_cond[i][n]   (fp32, tiny GEMM)
__global__ __launch_bounds__(256)
void cond_kernel(const float* __restrict__ c, const float* __restrict__ w,
                 float* __restrict__ cm) {
    __shared__ float sc[1024];
    const int b = blockIdx.y;
    for (int i = threadIdx.x; i < 1024; i += 256) {
        float v = c[b * 1024 + i];
        sc[i] = v / (1.f + expf(-v));
    }
    __syncthreads();
    const int col = blockIdx.x * 256 + threadIdx.x;
    float acc = 0.f;
    for (int i = 0; i < 1024; ++i) acc += sc[i] * w[(size_t)i * 6144 + col];
    cm[b * 6144 + col] = acc;
}

// ---------------------------------------------------------------------------
// LayerNorm (stats fp32, output cast bf16) then modulate (bf16 semantics).
__global__ __launch_bounds__(256)
void ln_mod_kernel(const float* __restrict__ x, const float* __restrict__ cm,
                   int shift0, int scale0, u16* __restrict__ out) {
    __shared__ float red[8];
    const int row = blockIdx.x, tid = threadIdx.x;
    const int b = row >> 10;
    const float4 v = *(const float4*)(x + (size_t)row * 1024 + tid * 4);
    float s = v.x + v.y + v.z + v.w;
#pragma unroll
    for (int mk = 1; mk < 64; mk <<= 1) s += __shfl_xor(s, mk);
    if ((tid & 63) == 0) red[tid >> 6] = s;
    __syncthreads();
    const float mean = (red[0] + red[1] + red[2] + red[3]) * (1.f / 1024.f);
    const float d0 = v.x - mean, d1 = v.y - mean, d2 = v.z - mean, d3 = v.w - mean;
    float ss = d0 * d0 + d1 * d1 + d2 * d2 + d3 * d3;
#pragma unroll
    for (int mk = 1; mk < 64; mk <<= 1) ss += __shfl_xor(ss, mk);
    if ((tid & 63) == 0) red[4 + (tid >> 6)] = ss;
    __syncthreads();
    const float var = (red[4] + red[5] + red[6] + red[7]) * (1.f / 1024.f);
    const float rs = rsqrtf(var + 1e-6f);
    const float* cmb = cm + b * 6144;
    const int c0 = tid * 4;
    ushort4 ov;
    ov.x = f2bf(bf2f(f2bf(d0 * rs)) * cmb[scale0 + c0 + 0] + cmb[shift0 + c0 + 0]);
    ov.y = f2bf(bf2f(f2bf(d1 * rs)) * cmb[scale0 + c0 + 1] + cmb[shift0 + c0 + 1]);
    ov.z = f2bf(bf2f(f2bf(d2 * rs)) * cmb[scale0 + c0 + 2] + cmb[shift0 + c0 + 2]);
    ov.w = f2bf(bf2f(f2bf(d3 * rs)) * cmb[scale0 + c0 + 3] + cmb[shift0 + c0 + 3]);
    *(ushort4*)(out + (size_t)row * 1024 + c0) = ov;
}

// ---------------------------------------------------------------------------
// fp32 (R,C) -> bf16 transposed (C,R).  block (32,8), grid (C/32, R/32)
__global__ __launch_bounds__(256)
void transpose_cast(const float* __restrict__ in, u16* __restrict__ out,
                    int R, int C) {
    __shared__ float t[32][33];
    const int tx = threadIdx.x, ty = threadIdx.y;
    const int c0 = blockIdx.x * 32, r0 = blockIdx.y * 32;
#pragma unroll
    for (int i = 0; i < 4; ++i)
        t[ty + i * 8][tx] = in[(size_t)(r0 + ty + i * 8) * C + c0 + tx];
    __syncthreads();
#pragma unroll
    for (int i = 0; i < 4; ++i)
        out[(size_t)(c0 + ty + i * 8) * R + r0 + tx] = f2bf(t[tx][ty + i * 8]);
}

// ---------------------------------------------------------------------------
// V slice of kqv -> vT[bh][d][s]  (bf16). block (32,8), grid (32, 2, 128)
__global__ __launch_bounds__(256)
void vtrans_kernel(const u16* __restrict__ kqv, u16* __restrict__ vT) {
    __shared__ u16 t[32][33];
    const int tx = threadIdx.x, ty = threadIdx.y;
    const int s0 = blockIdx.x * 32, d0 = blockIdx.y * 32;
    const int bh = blockIdx.z, b = bh >> 4, h = bh & 15;
#pragma unroll
    for (int i = 0; i < 4; ++i) {
        int s = s0 + ty + i * 8;
        t[ty + i * 8][tx] = kqv[(size_t)(b * 1024 + s) * 3072 + 2048 + h * 64 + d0 + tx];
    }
    __syncthreads();
#pragma unroll
    for (int i = 0; i < 4; ++i) {
        int d = d0 + ty + i * 8;
        vT[((size_t)bh * 64 + d) * 1024 + s0 + tx] = t[tx][ty + i * 8];
    }
}

// ---------------------------------------------------------------------------
// GEMM  C[M][N] = A[M][K] (bf16) @ BT[N][K]^T (bf16), 128x128 tile, BK=32,
// global_load_lds (width 16) staging (m97 pattern), 4 waves x 64x64.
template <int EPI>
__global__ __launch_bounds__(256)
void gemm_epi(const u16* __restrict__ A, const u16* __restrict__ BT,
              int M, int N, int K,
              u16* __restrict__ outb, float* __restrict__ outf,
              const float* __restrict__ resid, const float* __restrict__ gatec,
              float* __restrict__ stats, int* __restrict__ counts) {
    __shared__ u16 As[128 * 32];
    __shared__ u16 Bs[128 * 32];
    __shared__ float red[4];
    __shared__ int ccnt[128];

    const int tid = threadIdx.x;
    const int lane = tid & 63;
    const int wave = tid >> 6;
    const int wm = wave & 1, wn = wave >> 1;
    const int quad = lane >> 4, l15 = lane & 15;
    const int tm = blockIdx.y * 128, tn = blockIdx.x * 128;

    const int srow = tid >> 2;        // 0..63
    const int scol = (tid & 3) * 8;   // 0,8,16,24 (bf16 elems; 16B)

    f32x4 acc[4][4];
#pragma unroll
    for (int i = 0; i < 4; ++i)
#pragma unroll
        for (int j = 0; j < 4; ++j) acc[i][j] = (f32x4){0.f, 0.f, 0.f, 0.f};

    for (int k0 = 0; k0 < K; k0 += 32) {
        __syncthreads();
#pragma unroll
        for (int p = 0; p < 2; ++p) {
            const int r = p * 64 + srow;
            gld16(A + (size_t)(tm + r) * K + k0 + scol, As + p * 2048 + wave * 512);
            gld16(BT + (size_t)(tn + r) * K + k0 + scol, Bs + p * 2048 + wave * 512);
        }
        __syncthreads();
        V8 af[4], bfr[4];
#pragma unroll
        for (int i = 0; i < 4; ++i)
            af[i].u = *(const u16x8*)(As + (wm * 64 + i * 16 + l15) * 32 + quad * 8);
#pragma unroll
        for (int j = 0; j < 4; ++j)
            bfr[j].u = *(const u16x8*)(Bs + (wn * 64 + j * 16 + l15) * 32 + quad * 8);
#pragma unroll
        for (int i = 0; i < 4; ++i)
#pragma unroll
            for (int j = 0; j < 4; ++j)
                acc[i][j] = __builtin_amdgcn_mfma_f32_16x16x32_bf16(
                    af[i].b, bfr[j].b, acc[i][j], 0, 0, 0);
    }

    if (EPI == 2) {
        for (int i = tid; i < 128; i += 256) ccnt[i] = 0;
    }
    __syncthreads();

    float s0 = 0.f, s1 = 0.f, s2 = 0.f;
#pragma unroll
    for (int i = 0; i < 4; ++i) {
#pragma unroll
        for (int j = 0; j < 4; ++j) {
#pragma unroll
            for (int r = 0; r < 4; ++r) {
                const int row = tm + wm * 64 + i * 16 + quad * 4 + r;
                const int col = tn + wn * 64 + j * 16 + l15;
                const float v = acc[i][j][r];
                const size_t idx = (size_t)row * N + col;
                if (EPI == 0) {
                    outb[idx] = f2bf(v);
                } else if (EPI == 1) {
                    const int bb = row >> 10;
                    const float g = gatec[bb * 6144 + col];
                    const float xa = g * v;
                    const float xv = resid[idx];
                    const float o = xv + xa;
                    outf[idx] = o;
                    s0 += xa * xa; s1 += xv * xv; s2 += o * o;
                } else if (EPI == 2) {
                    if (v > 0.f) atomicAdd(&ccnt[wn * 64 + j * 16 + l15], 1);
                    s0 += v * v;
                    const float a = fminf(0.7978845608028654f * (v + 0.044715f * v * v * v), 40.f);
                    const float e = __expf(2.f * a);
                    outb[idx] = f2bf(v * e / (e + 1.f));
                } else {
                    const int bb = row >> 10;
                    const float g = gatec[bb * 6144 + col];
                    const float xm = g * v;
                    const float o = resid[idx] + xm;
                    outf[idx] = o;
                    s0 += xm * xm;
                }
            }
        }
    }

    if (EPI == 1) {
        float t = block_sum256(s0, red); if (tid == 0) atomicAdd(&stats[0], t);
        t = block_sum256(s1, red);       if (tid == 0) atomicAdd(&stats[1], t);
        t = block_sum256(s2, red);       if (tid == 0) atomicAdd(&stats[2], t);
    } else if (EPI == 2) {
        __syncthreads();
        for (int i = tid; i < 128; i += 256) atomicAdd(&counts[tn + i], ccnt[i]);
        float t = block_sum256(s0, red); if (tid == 0) atomicAdd(&stats[3], t);
    } else if (EPI == 3) {
        float t = block_sum256(s0, red); if (tid == 0) atomicAdd(&stats[4], t);
    }
}

// ---------------------------------------------------------------------------
// Flash attention v3: keys split across waves, q-rows shared.
// grid (16 qtiles, 128 bh), block 256. Block owns 64 q rows; wave w owns the
// 32-key slice [w*32, w*32+32) of every 128-key tile, maintaining partial
// (m, l, O^T) over its 256 keys; partials merged at the end (flash merge).
//  - S^T = K·Q^T  -> key-reduction = 8 in-lane + 2 shuffles (xor16/xor32)
//  - O^T = V^T·P^T with swizzled wave-private P round-trip (2-way banks)
// LDS reads/wave/k0: 4 K-frag + 4 P-frag + 4 V-frag b128 (3x less than v2).
__global__ __launch_bounds__(256, 2)
void attn_kernel(const u16* __restrict__ kqv, const u16* __restrict__ vT,
                 u16* __restrict__ y, float* __restrict__ stats) {
    __shared__ __align__(16) char smem[49152];
    u16* Ks = (u16*)smem;              // 16 KB  [128 k][8 ch^(k&7)]
    u16* Vs = (u16*)(smem + 16384);    // 16 KB  [64 d][16 ch^(d&15)]
    u16* P  = (u16*)(smem + 32768);    // 16 KB  per-wave 4 KB [64 q][4 ch^fq]
    float* obuf = (float*)smem;                  // merge overlay: [64 q][72]
    float* mlb  = (float*)(smem + 32768);        // merge overlay: m[16][16], l[16][16]
    float* lbuf = (float*)(smem + 32768 + 2048); // merge overlay: 1/L per q

    const int tid = threadIdx.x, lane = tid & 63, w = tid >> 6;
    const int quad = lane >> 4, l15 = lane & 15;
    const int bh = blockIdx.y, b = bh >> 4, h = bh & 15;
    const int qbase = blockIdx.x * 64;
    const int fq = (l15 >> 1) & 3;     // P chunk swizzle (depends on q&15 only)

    // Q b-frags for all 64 q rows (one-time scattered global loads)
    V8 qf[4][2];
#pragma unroll
    for (int qt = 0; qt < 4; ++qt) {
        const size_t rq = ((size_t)(b * 1024 + qbase + qt * 16 + l15)) * 3072
                        + 1024 + h * 64 + quad * 8;
        qf[qt][0].u = *(const u16x8*)(kqv + rq);
        qf[qt][1].u = *(const u16x8*)(kqv + rq + 32);
    }

    float m[4], l[4];
    f32x4 o[4][4];                     // o[dt][qt]: O^T[d=dt*16+quad*4+r][q=qt*16+l15]
#pragma unroll
    for (int qt = 0; qt < 4; ++qt) { m[qt] = -__builtin_inff(); l[qt] = 0.f; }
#pragma unroll
    for (int dt = 0; dt < 4; ++dt)
#pragma unroll
        for (int qt = 0; qt < 4; ++qt) o[dt][qt] = (f32x4){0.f, 0.f, 0.f, 0.f};

    u16* wp = P + w * 2048;
    const size_t kbase = (size_t)(b * 1024) * 3072 + h * 64;
    const size_t vbase = (size_t)bh * 65536;

    for (int k0 = 0; k0 < 1024; k0 += 128) {
        __syncthreads();               // all waves done reading previous Ks/Vs
#pragma unroll
        for (int i = 0; i < 4; ++i) {
            const int c = i * 256 + tid;
            {   // K tile: 128 rows x 8 chunks, col swizzle ^(row&7)
                const int row = c >> 3, col8 = (c & 7) ^ (row & 7);
                gld16(kqv + kbase + (size_t)(k0 + row) * 3072 + col8 * 8,
                      Ks + (i * 256 + w * 64) * 8);
            }
            {   // V tile: 64 rows x 16 chunks, col swizzle ^(d&15)
                const int d = c >> 4, col8 = (c & 15) ^ (d & 15);
                gld16(vT + vbase + (size_t)d * 1024 + k0 + col8 * 8,
                      Vs + (i * 256 + w * 64) * 8);
            }
        }
        __syncthreads();               // staged loads visible

        // ---- S^T = K·Q^T for this wave's 32 keys x 64 q rows ----
        f32x4 s[2][4];
#pragma unroll
        for (int kt = 0; kt < 2; ++kt) {
            const int krow = w * 32 + kt * 16 + l15;
            V8 ak0, ak1;
            ak0.u = *(const u16x8*)(Ks + krow * 64 + ((quad ^ (l15 & 7)) * 8));
            ak1.u = *(const u16x8*)(Ks + krow * 64 + (((quad + 4) ^ (l15 & 7)) * 8));
#pragma unroll
            for (int qt = 0; qt < 4; ++qt) {
                s[kt][qt] = __builtin_amdgcn_mfma_f32_16x16x32_bf16(
                    ak0.b, qf[qt][0].b, (f32x4){0.f, 0.f, 0.f, 0.f}, 0, 0, 0);
                s[kt][qt] = __builtin_amdgcn_mfma_f32_16x16x32_bf16(
                    ak1.b, qf[qt][1].b, s[kt][qt], 0, 0, 0);
            }
        }

        // ---- online softmax (keys in-lane + across quads) ----
#pragma unroll
        for (int qt = 0; qt < 4; ++qt) {
            float mx = s[0][qt][0];
            mx = fmaxf(mx, s[0][qt][1]); mx = fmaxf(mx, s[0][qt][2]);
            mx = fmaxf(mx, s[0][qt][3]); mx = fmaxf(mx, s[1][qt][0]);
            mx = fmaxf(mx, s[1][qt][1]); mx = fmaxf(mx, s[1][qt][2]);
            mx = fmaxf(mx, s[1][qt][3]);
            mx *= 0.125f;
            mx = fmaxf(mx, __shfl_xor(mx, 16));
            mx = fmaxf(mx, __shfl_xor(mx, 32));
            const float mn = fmaxf(m[qt], mx);
            const float alpha = __expf(m[qt] - mn);
            float ps = 0.f;
            u16 pr[2][4];
#pragma unroll
            for (int kt = 0; kt < 2; ++kt)
#pragma unroll
                for (int r = 0; r < 4; ++r) {
                    const float p = __expf(s[kt][qt][r] * 0.125f - mn);
                    ps += p;
                    pr[kt][r] = f2bf(p);
                }
            ps += __shfl_xor(ps, 16);
            ps += __shfl_xor(ps, 32);
            l[qt] = l[qt] * alpha + ps;
            m[qt] = mn;
#pragma unroll
            for (int dt = 0; dt < 4; ++dt) o[dt][qt] *= alpha;
            // P^T write: q=qt*16+l15, wave-rel keys kt*16+quad*4+{0..3}, b32 pairs
            const int qrow = qt * 16 + l15;
#pragma unroll
            for (int kt = 0; kt < 2; ++kt) {
                const int c0 = (kt * 2 + (quad >> 1)) ^ fq;
                u16* pdst = wp + qrow * 32 + c0 * 8 + (quad & 1) * 4;
                *(unsigned*)(pdst)     = (unsigned)pr[kt][0] | ((unsigned)pr[kt][1] << 16);
                *(unsigned*)(pdst + 2) = (unsigned)pr[kt][2] | ((unsigned)pr[kt][3] << 16);
            }
        }

        // ---- O^T += V^T · P^T (wave-private P; no barrier) ----
        V8 pb[4];
#pragma unroll
        for (int qt = 0; qt < 4; ++qt)
            pb[qt].u = *(const u16x8*)(wp + (qt * 16 + l15) * 32 + ((quad ^ fq) * 8));
#pragma unroll
        for (int dt = 0; dt < 4; ++dt) {
            V8 av;
            av.u = *(const u16x8*)(Vs + (dt * 16 + l15) * 128 + (((w * 4 + quad) ^ l15) * 8));
#pragma unroll
            for (int qt = 0; qt < 4; ++qt)
                o[dt][qt] = __builtin_amdgcn_mfma_f32_16x16x32_bf16(
                    av.b, pb[qt].b, o[dt][qt], 0, 0, 0);
        }
    }

    // ================= flash merge of the 4 per-wave partials =================
    __syncthreads();                   // Ks/Vs/P dead -> overlay
    if (quad == 0) {
#pragma unroll
        for (int qt = 0; qt < 4; ++qt) {
            mlb[(w * 4 + qt) * 16 + l15] = m[qt];
            mlb[256 + (w * 4 + qt) * 16 + l15] = l[qt];
        }
    }
    __syncthreads();
    float scale[4];
#pragma unroll
    for (int qt = 0; qt < 4; ++qt) {
        float M = -__builtin_inff();
#pragma unroll
        for (int ww = 0; ww < 4; ++ww) M = fmaxf(M, mlb[(ww * 4 + qt) * 16 + l15]);
        float L = 0.f;
#pragma unroll
        for (int ww = 0; ww < 4; ++ww)
            L += mlb[256 + (ww * 4 + qt) * 16 + l15] *
                 __expf(mlb[(ww * 4 + qt) * 16 + l15] - M);
        scale[qt] = __expf(m[qt] - M);
        if (w == 0 && quad == 0) lbuf[qt * 16 + l15] = 1.f / L;
    }
    for (int ww = 0; ww < 4; ++ww) {   // sequential accumulate into obuf
        if (ww == w) {
#pragma unroll
            for (int qt = 0; qt < 4; ++qt) {
                float* dst = obuf + (qt * 16 + l15) * 72 + quad * 4;
#pragma unroll
                for (int dt = 0; dt < 4; ++dt) {
                    f32x4 v = o[dt][qt] * scale[qt];
                    if (ww != 0) v += *(f32x4*)(dst + dt * 16);
                    *(f32x4*)(dst + dt * 16) = v;
                }
            }
        }
        __syncthreads();
    }
    if (w == 0) {                      // sum of 1/L over the 64 q rows
        float sv = lbuf[lane];
#pragma unroll
        for (int mk = 1; mk < 64; mk <<= 1) sv += __shfl_xor(sv, mk);
        if (lane == 0) atomicAdd(&stats[5], sv);
    }
    // normalize + coalesced store: thread -> (q = tid>>2, 16 d's)
    {
        const int q = tid >> 2, dseg = (tid & 3) * 16;
        const float il = lbuf[q];
        const float* src = obuf + q * 72 + dseg;
        __align__(16) u16 tmp[16];
#pragma unroll
        for (int j = 0; j < 16; ++j) tmp[j] = f2bf(src[j] * il);
        u16* ydst = y + ((size_t)(b * 1024 + qbase + q)) * 1024 + h * 64 + dseg;
        *(uint4*)(ydst) = *(uint4*)(tmp);
        *(uint4*)(ydst + 8) = *(uint4*)(tmp + 8);
    }
}

// ---------------------------------------------------------------------------
__global__ __launch_bounds__(256)
void finalize_kernel(const int* __restrict__ counts, const float* __restrict__ stats,
                     float* __restrict__ out7) {
    __shared__ float red[4];
    float d = 0.f, z = 0.f, pp = 0.f;
    for (int i = threadIdx.x; i < 4096; i += 256) {
        const int c = counts[i];
        const float frac = (float)c * (1.f / 8192.f);
        d += fabsf(frac - 0.5f);
        z += (c == 0) ? 1.f : 0.f;
        pp += (c == 8192) ? 1.f : 0.f;
    }
    d = block_sum256(d, red);
    z = block_sum256(z, red);
    pp = block_sum256(pp, red);
    if (threadIdx.x == 0) {
        out7[0] = d * (1.f / 4096.f);
        out7[1] = z * (1.f / 4096.f);
        out7[2] = pp * (1.f / 4096.f);
        out7[3] = stats[5] * (1.f / 131072.f);
        out7[4] = sqrtf(stats[0] / stats[1]);
        out7[5] = sqrtf(stats[4] / stats[2]);
        out7[6] = sqrtf(stats[3] / (8192.f * 4096.f));
    }
}

// ---------------------------------------------------------------------------
extern "C" void kernel_launch(void* const* d_in, const int* in_sizes, int n_in,
                              void* d_out, int out_size, void* d_ws, size_t ws_size,
                              hipStream_t stream) {
    const float* x      = (const float*)d_in[0];
    const float* c      = (const float*)d_in[1];
    const float* w_cond = (const float*)d_in[2];
    const float* w_qkv  = (const float*)d_in[3];
    const float* w_attn = (const float*)d_in[4];
    const float* w_mlp1 = (const float*)d_in[5];
    const float* w_mlp2 = (const float*)d_in[6];
    float* out = (float*)d_out;

    char* base = (char*)d_ws;
    size_t off = 0;
    auto alloc = [&](size_t n) { void* r = base + off; off += (n + 255) & ~(size_t)255; return r; };
    float* stats   = (float*)alloc(64);
    int*   counts  = (int*)alloc(4096 * 4);
    float* cm      = (float*)alloc((size_t)8 * 6144 * 4);
    u16*   x_mod   = (u16*)alloc((size_t)8192 * 1024 * 2);
    u16*   kqv     = (u16*)alloc((size_t)8192 * 3072 * 2);
    u16*   vT      = (u16*)alloc((size_t)128 * 64 * 1024 * 2);
    u16*   y       = (u16*)alloc((size_t)8192 * 1024 * 2);
    float* x1      = (float*)alloc((size_t)8192 * 1024 * 4);
    u16*   wt_qkv  = (u16*)alloc((size_t)3072 * 1024 * 2);
    u16*   wt_attn = (u16*)alloc((size_t)1024 * 1024 * 2);
    u16*   wt_mlp1 = (u16*)alloc((size_t)4096 * 1024 * 2);
    u16*   wt_mlp2 = (u16*)alloc((size_t)1024 * 4096 * 2);
    u16*   h_act   = kqv;
    u16*   x_mod2  = x_mod;
    (void)vT; (void)ws_size; (void)n_in; (void)in_sizes; (void)out_size;

    hipMemsetAsync(d_ws, 0, 256 + 4096 * 4, stream);

    dim3 tb(32, 8);
    transpose_cast<<<dim3(3072 / 32, 1024 / 32), tb, 0, stream>>>(w_qkv,  wt_qkv,  1024, 3072);
    transpose_cast<<<dim3(1024 / 32, 1024 / 32), tb, 0, stream>>>(w_attn, wt_attn, 1024, 1024);
    transpose_cast<<<dim3(4096 / 32, 1024 / 32), tb, 0, stream>>>(w_mlp1, wt_mlp1, 1024, 4096);
    transpose_cast<<<dim3(1024 / 32, 4096 / 32), tb, 0, stream>>>(w_mlp2, wt_mlp2, 4096, 1024);

    cond_kernel<<<dim3(24, 8), 256, 0, stream>>>(c, w_cond, cm);

    ln_mod_kernel<<<8192, 256, 0, stream>>>(x, cm, 0, 1024, x_mod);

    gemm_epi<0><<<dim3(3072 / 128, 8192 / 128), 256, 0, stream>>>(
        x_mod, wt_qkv, 8192, 3072, 1024, kqv, nullptr, nullptr, nullptr, stats, nullptr);

    vtrans_kernel<<<dim3(32, 2, 128), tb, 0, stream>>>(kqv, vT);

    attn_kernel<<<dim3(16, 128), 256, 0, stream>>>(kqv, vT, y, stats);

    gemm_epi<1><<<dim3(1024 / 128, 8192 / 128), 256, 0, stream>>>(
        y, wt_attn, 8192, 1024, 1024, nullptr, x1, x, cm + 2 * 1024, stats, nullptr);

    ln_mod_kernel<<<8192, 256, 0, stream>>>(x1, cm, 3 * 1024, 4 * 1024, x_mod2);

    gemm_epi<2><<<dim3(4096 / 128, 8192 / 128), 256, 0, stream>>>(
        x_mod2, wt_mlp1, 8192, 4096, 1024, h_act, nullptr, nullptr, nullptr, stats, counts);

    gemm_epi<3><<<dim3(1024 / 128, 8192 / 128), 256, 0, stream>>>(
        h_act, wt_mlp2, 8192, 1024, 4096, nullptr, out, x1, cm + 5 * 1024, stats, nullptr);

    finalize_kernel<<<1, 256, 0, stream>>>(counts, stats, out + (size_t)8192 * 1024);
}

// Round 4
// 627.989 us; speedup vs baseline: 1.3740x; 1.0399x over previous
//
#include <hip/hip_runtime.h>

typedef unsigned short u16;
typedef __bf16 bf16x8 __attribute__((ext_vector_type(8)));
typedef unsigned short u16x8 __attribute__((ext_vector_type(8)));
typedef float f32x4 __attribute__((ext_vector_type(4)));

union V8 { u16x8 u; bf16x8 b; };

__device__ __forceinline__ u16 f2bf(float f) {
    unsigned u = __float_as_uint(f);
    u += 0x7fffu + ((u >> 16) & 1u);
    return (u16)(u >> 16);
}
__device__ __forceinline__ float bf2f(u16 h) {
    return __uint_as_float(((unsigned)h) << 16);
}

// async global->LDS, 16B per lane. LDS dest = wave-uniform base + lane*16.
__device__ __forceinline__ void gld16(const void* g, void* l) {
    __builtin_amdgcn_global_load_lds(
        (const __attribute__((address_space(1))) void*)g,
        (__attribute__((address_space(3))) void*)l, 16, 0, 0);
}

// block-wide sum for blockDim.x == 256 (4 waves). Returns total to all threads.
__device__ __forceinline__ float block_sum256(float v, float* red) {
#pragma unroll
    for (int mk = 1; mk < 64; mk <<= 1) v += __shfl_xor(v, mk);
    __syncthreads();                  // protect red reuse across calls
    if ((threadIdx.x & 63) == 0) red[threadIdx.x >> 6] = v;
    __syncthreads();
    return red[0] + red[1] + red[2] + red[3];
}

// ---------------------------------------------------------------------------
// cond: cm[b][n] = sum_i silu(c[b][i]) * w_cond[i][n]   (fp32, tiny GEMM)
__global__ __launch_bounds__(256)
void cond_kernel(const float* __restrict__ c, const float* __restrict__ w,
                 float* __restrict__ cm) {
    __shared__ float sc[1024];
    const int b = blockIdx.y;
    for (int i = threadIdx.x; i < 1024; i += 256) {
        float v = c[b * 1024 + i];
        sc[i] = v / (1.f + expf(-v));
    }
    __syncthreads();
    const int col = blockIdx.x * 256 + threadIdx.x;
    float acc = 0.f;
    for (int i = 0; i < 1024; ++i) acc += sc[i] * w[(size_t)i * 6144 + col];
    cm[b * 6144 + col] = acc;
}

// ---------------------------------------------------------------------------
// LayerNorm (stats fp32, output cast bf16) then modulate (bf16 semantics).
__global__ __launch_bounds__(256)
void ln_mod_kernel(const float* __restrict__ x, const float* __restrict__ cm,
                   int shift0, int scale0, u16* __restrict__ out) {
    __shared__ float red[8];
    const int row = blockIdx.x, tid = threadIdx.x;
    const int b = row >> 10;
    const float4 v = *(const float4*)(x + (size_t)row * 1024 + tid * 4);
    float s = v.x + v.y + v.z + v.w;
#pragma unroll
    for (int mk = 1; mk < 64; mk <<= 1) s += __shfl_xor(s, mk);
    if ((tid & 63) == 0) red[tid >> 6] = s;
    __syncthreads();
    const float mean = (red[0] + red[1] + red[2] + red[3]) * (1.f / 1024.f);
    const float d0 = v.x - mean, d1 = v.y - mean, d2 = v.z - mean, d3 = v.w - mean;
    float ss = d0 * d0 + d1 * d1 + d2 * d2 + d3 * d3;
#pragma unroll
    for (int mk = 1; mk < 64; mk <<= 1) ss += __shfl_xor(ss, mk);
    if ((tid & 63) == 0) red[4 + (tid >> 6)] = ss;
    __syncthreads();
    const float var = (red[4] + red[5] + red[6] + red[7]) * (1.f / 1024.f);
    const float rs = rsqrtf(var + 1e-6f);
    const float* cmb = cm + b * 6144;
    const int c0 = tid * 4;
    ushort4 ov;
    ov.x = f2bf(bf2f(f2bf(d0 * rs)) * cmb[scale0 + c0 + 0] + cmb[shift0 + c0 + 0]);
    ov.y = f2bf(bf2f(f2bf(d1 * rs)) * cmb[scale0 + c0 + 1] + cmb[shift0 + c0 + 1]);
    ov.z = f2bf(bf2f(f2bf(d2 * rs)) * cmb[scale0 + c0 + 2] + cmb[shift0 + c0 + 2]);
    ov.w = f2bf(bf2f(f2bf(d3 * rs)) * cmb[scale0 + c0 + 3] + cmb[shift0 + c0 + 3]);
    *(ushort4*)(out + (size_t)row * 1024 + c0) = ov;
}

// ---------------------------------------------------------------------------
// fp32 (R,C) -> bf16 transposed (C,R).  block (32,8), grid (C/32, R/32)
__global__ __launch_bounds__(256)
void transpose_cast(const float* __restrict__ in, u16* __restrict__ out,
                    int R, int C) {
    __shared__ float t[32][33];
    const int tx = threadIdx.x, ty = threadIdx.y;
    const int c0 = blockIdx.x * 32, r0 = blockIdx.y * 32;
#pragma unroll
    for (int i = 0; i < 4; ++i)
        t[ty + i * 8][tx] = in[(size_t)(r0 + ty + i * 8) * C + c0 + tx];
    __syncthreads();
#pragma unroll
    for (int i = 0; i < 4; ++i)
        out[(size_t)(c0 + ty + i * 8) * R + r0 + tx] = f2bf(t[tx][ty + i * 8]);
}

// ---------------------------------------------------------------------------
// V slice of kqv -> vT[bh][d][s]  (bf16). block (32,8), grid (32, 2, 128)
__global__ __launch_bounds__(256)
void vtrans_kernel(const u16* __restrict__ kqv, u16* __restrict__ vT) {
    __shared__ u16 t[32][33];
    const int tx = threadIdx.x, ty = threadIdx.y;
    const int s0 = blockIdx.x * 32, d0 = blockIdx.y * 32;
    const int bh = blockIdx.z, b = bh >> 4, h = bh & 15;
#pragma unroll
    for (int i = 0; i < 4; ++i) {
        int s = s0 + ty + i * 8;
        t[ty + i * 8][tx] = kqv[(size_t)(b * 1024 + s) * 3072 + 2048 + h * 64 + d0 + tx];
    }
    __syncthreads();
#pragma unroll
    for (int i = 0; i < 4; ++i) {
        int d = d0 + ty + i * 8;
        vT[((size_t)bh * 64 + d) * 1024 + s0 + tx] = t[tx][ty + i * 8];
    }
}

// ---------------------------------------------------------------------------
// GEMM  C[M][N] = A[M][K] (bf16) @ BT[N][K]^T (bf16), 128x128 tile, BK=32,
// global_load_lds staging with bank-swizzled LDS content:
//   LDS[row][c'] holds global chunk c'^((row>>1)&3)  (16B chunks, 4/row)
// -> fragment read addr row*64B + (quad^((l15>>1)&3))*16B: every 8
//    consecutive lanes hit 8 distinct 4-bank groups (conflict-free).
// Grid: blockIdx.x = m_tile (fast) so the blocks sharing an A-strip have
// bid = n*gridX + m == m (mod 8) -> same XCD -> A fetched once per XCD.
template <int EPI>
__global__ __launch_bounds__(256)
void gemm_epi(const u16* __restrict__ A, const u16* __restrict__ BT,
              int M, int N, int K,
              u16* __restrict__ outb, float* __restrict__ outf,
              const float* __restrict__ resid, const float* __restrict__ gatec,
              float* __restrict__ stats, int* __restrict__ counts) {
    __shared__ u16 As[128 * 32];
    __shared__ u16 Bs[128 * 32];
    __shared__ float red[4];
    __shared__ int ccnt[128];

    const int tid = threadIdx.x;
    const int lane = tid & 63;
    const int wave = tid >> 6;
    const int wm = wave & 1, wn = wave >> 1;
    const int quad = lane >> 4, l15 = lane & 15;
    const int tm = blockIdx.x * 128, tn = blockIdx.y * 128;

    const int srow = tid >> 2;                        // 0..63
    const int scol = (((tid & 3) ^ ((srow >> 1) & 3))) * 8;  // swizzled chunk
    const int rsw = (l15 >> 1) & 3;                   // frag-read swizzle

    f32x4 acc[4][4];
#pragma unroll
    for (int i = 0; i < 4; ++i)
#pragma unroll
        for (int j = 0; j < 4; ++j) acc[i][j] = (f32x4){0.f, 0.f, 0.f, 0.f};

    for (int k0 = 0; k0 < K; k0 += 32) {
        __syncthreads();
#pragma unroll
        for (int p = 0; p < 2; ++p) {
            const int r = p * 64 + srow;              // p*64 keeps row bits 1..2
            gld16(A + (size_t)(tm + r) * K + k0 + scol, As + p * 2048 + wave * 512);
            gld16(BT + (size_t)(tn + r) * K + k0 + scol, Bs + p * 2048 + wave * 512);
        }
        __syncthreads();
        V8 af[4], bfr[4];
#pragma unroll
        for (int i = 0; i < 4; ++i)
            af[i].u = *(const u16x8*)(As + (wm * 64 + i * 16 + l15) * 32 + ((quad ^ rsw) * 8));
#pragma unroll
        for (int j = 0; j < 4; ++j)
            bfr[j].u = *(const u16x8*)(Bs + (wn * 64 + j * 16 + l15) * 32 + ((quad ^ rsw) * 8));
#pragma unroll
        for (int i = 0; i < 4; ++i)
#pragma unroll
            for (int j = 0; j < 4; ++j)
                acc[i][j] = __builtin_amdgcn_mfma_f32_16x16x32_bf16(
                    af[i].b, bfr[j].b, acc[i][j], 0, 0, 0);
    }

    if (EPI == 2) {
        for (int i = tid; i < 128; i += 256) ccnt[i] = 0;
    }
    __syncthreads();

    float s0 = 0.f, s1 = 0.f, s2 = 0.f;
    int cj[4] = {0, 0, 0, 0};
#pragma unroll
    for (int i = 0; i < 4; ++i) {
#pragma unroll
        for (int j = 0; j < 4; ++j) {
#pragma unroll
            for (int r = 0; r < 4; ++r) {
                const int row = tm + wm * 64 + i * 16 + quad * 4 + r;
                const int col = tn + wn * 64 + j * 16 + l15;
                const float v = acc[i][j][r];
                const size_t idx = (size_t)row * N + col;
                if (EPI == 0) {
                    outb[idx] = f2bf(v);
                } else if (EPI == 1) {
                    const int bb = row >> 10;
                    const float g = gatec[bb * 6144 + col];
                    const float xa = g * v;
                    const float xv = resid[idx];
                    const float o = xv + xa;
                    outf[idx] = o;
                    s0 += xa * xa; s1 += xv * xv; s2 += o * o;
                } else if (EPI == 2) {
                    cj[j] += (v > 0.f) ? 1 : 0;
                    s0 += v * v;
                    const float a = fminf(0.7978845608028654f * (v + 0.044715f * v * v * v), 40.f);
                    const float e = __expf(2.f * a);
                    outb[idx] = f2bf(v * e / (e + 1.f));
                } else {
                    const int bb = row >> 10;
                    const float g = gatec[bb * 6144 + col];
                    const float xm = g * v;
                    const float o = resid[idx] + xm;
                    outf[idx] = o;
                    s0 += xm * xm;
                }
            }
        }
    }

    if (EPI == 1) {
        float t = block_sum256(s0, red); if (tid == 0) atomicAdd(&stats[0], t);
        t = block_sum256(s1, red);       if (tid == 0) atomicAdd(&stats[1], t);
        t = block_sum256(s2, red);       if (tid == 0) atomicAdd(&stats[2], t);
    } else if (EPI == 2) {
        // per-column positive counts: reduce across quads, 1 atomic per column
#pragma unroll
        for (int j = 0; j < 4; ++j) {
            int c = cj[j];
            c += __shfl_xor(c, 16);
            c += __shfl_xor(c, 32);
            if (quad == 0) atomicAdd(&ccnt[wn * 64 + j * 16 + l15], c);
        }
        __syncthreads();
        for (int i = tid; i < 128; i += 256) atomicAdd(&counts[tn + i], ccnt[i]);
        float t = block_sum256(s0, red); if (tid == 0) atomicAdd(&stats[3], t);
    } else if (EPI == 3) {
        float t = block_sum256(s0, red); if (tid == 0) atomicAdd(&stats[4], t);
    }
}

// ---------------------------------------------------------------------------
// Flash attention v3: keys split across waves, q-rows shared. (unchanged)
__global__ __launch_bounds__(256, 2)
void attn_kernel(const u16* __restrict__ kqv, const u16* __restrict__ vT,
                 u16* __restrict__ y, float* __restrict__ stats) {
    __shared__ __align__(16) char smem[49152];
    u16* Ks = (u16*)smem;              // 16 KB  [128 k][8 ch^(k&7)]
    u16* Vs = (u16*)(smem + 16384);    // 16 KB  [64 d][16 ch^(d&15)]
    u16* P  = (u16*)(smem + 32768);    // 16 KB  per-wave 4 KB [64 q][4 ch^fq]
    float* obuf = (float*)smem;                  // merge overlay: [64 q][72]
    float* mlb  = (float*)(smem + 32768);        // merge overlay: m/l [16][16]
    float* lbuf = (float*)(smem + 32768 + 2048); // merge overlay: 1/L per q

    const int tid = threadIdx.x, lane = tid & 63, w = tid >> 6;
    const int quad = lane >> 4, l15 = lane & 15;
    const int bh = blockIdx.y, b = bh >> 4, h = bh & 15;
    const int qbase = blockIdx.x * 64;
    const int fq = (l15 >> 1) & 3;

    V8 qf[4][2];
#pragma unroll
    for (int qt = 0; qt < 4; ++qt) {
        const size_t rq = ((size_t)(b * 1024 + qbase + qt * 16 + l15)) * 3072
                        + 1024 + h * 64 + quad * 8;
        qf[qt][0].u = *(const u16x8*)(kqv + rq);
        qf[qt][1].u = *(const u16x8*)(kqv + rq + 32);
    }

    float m[4], l[4];
    f32x4 o[4][4];
#pragma unroll
    for (int qt = 0; qt < 4; ++qt) { m[qt] = -__builtin_inff(); l[qt] = 0.f; }
#pragma unroll
    for (int dt = 0; dt < 4; ++dt)
#pragma unroll
        for (int qt = 0; qt < 4; ++qt) o[dt][qt] = (f32x4){0.f, 0.f, 0.f, 0.f};

    u16* wp = P + w * 2048;
    const size_t kbase = (size_t)(b * 1024) * 3072 + h * 64;
    const size_t vbase = (size_t)bh * 65536;

    for (int k0 = 0; k0 < 1024; k0 += 128) {
        __syncthreads();
#pragma unroll
        for (int i = 0; i < 4; ++i) {
            const int c = i * 256 + tid;
            {
                const int row = c >> 3, col8 = (c & 7) ^ (row & 7);
                gld16(kqv + kbase + (size_t)(k0 + row) * 3072 + col8 * 8,
                      Ks + (i * 256 + w * 64) * 8);
            }
            {
                const int d = c >> 4, col8 = (c & 15) ^ (d & 15);
                gld16(vT + vbase + (size_t)d * 1024 + k0 + col8 * 8,
                      Vs + (i * 256 + w * 64) * 8);
            }
        }
        __syncthreads();

        f32x4 s[2][4];
#pragma unroll
        for (int kt = 0; kt < 2; ++kt) {
            const int krow = w * 32 + kt * 16 + l15;
            V8 ak0, ak1;
            ak0.u = *(const u16x8*)(Ks + krow * 64 + ((quad ^ (l15 & 7)) * 8));
            ak1.u = *(const u16x8*)(Ks + krow * 64 + (((quad + 4) ^ (l15 & 7)) * 8));
#pragma unroll
            for (int qt = 0; qt < 4; ++qt) {
                s[kt][qt] = __builtin_amdgcn_mfma_f32_16x16x32_bf16(
                    ak0.b, qf[qt][0].b, (f32x4){0.f, 0.f, 0.f, 0.f}, 0, 0, 0);
                s[kt][qt] = __builtin_amdgcn_mfma_f32_16x16x32_bf16(
                    ak1.b, qf[qt][1].b, s[kt][qt], 0, 0, 0);
            }
        }

#pragma unroll
        for (int qt = 0; qt < 4; ++qt) {
            float mx = s[0][qt][0];
            mx = fmaxf(mx, s[0][qt][1]); mx = fmaxf(mx, s[0][qt][2]);
            mx = fmaxf(mx, s[0][qt][3]); mx = fmaxf(mx, s[1][qt][0]);
            mx = fmaxf(mx, s[1][qt][1]); mx = fmaxf(mx, s[1][qt][2]);
            mx = fmaxf(mx, s[1][qt][3]);
            mx *= 0.125f;
            mx = fmaxf(mx, __shfl_xor(mx, 16));
            mx = fmaxf(mx, __shfl_xor(mx, 32));
            const float mn = fmaxf(m[qt], mx);
            const float alpha = __expf(m[qt] - mn);
            float ps = 0.f;
            u16 pr[2][4];
#pragma unroll
            for (int kt = 0; kt < 2; ++kt)
#pragma unroll
                for (int r = 0; r < 4; ++r) {
                    const float p = __expf(s[kt][qt][r] * 0.125f - mn);
                    ps += p;
                    pr[kt][r] = f2bf(p);
                }
            ps += __shfl_xor(ps, 16);
            ps += __shfl_xor(ps, 32);
            l[qt] = l[qt] * alpha + ps;
            m[qt] = mn;
#pragma unroll
            for (int dt = 0; dt < 4; ++dt) o[dt][qt] *= alpha;
            const int qrow = qt * 16 + l15;
#pragma unroll
            for (int kt = 0; kt < 2; ++kt) {
                const int c0 = (kt * 2 + (quad >> 1)) ^ fq;
                u16* pdst = wp + qrow * 32 + c0 * 8 + (quad & 1) * 4;
                *(unsigned*)(pdst)     = (unsigned)pr[kt][0] | ((unsigned)pr[kt][1] << 16);
                *(unsigned*)(pdst + 2) = (unsigned)pr[kt][2] | ((unsigned)pr[kt][3] << 16);
            }
        }

        V8 pb[4];
#pragma unroll
        for (int qt = 0; qt < 4; ++qt)
            pb[qt].u = *(const u16x8*)(wp + (qt * 16 + l15) * 32 + ((quad ^ fq) * 8));
#pragma unroll
        for (int dt = 0; dt < 4; ++dt) {
            V8 av;
            av.u = *(const u16x8*)(Vs + (dt * 16 + l15) * 128 + (((w * 4 + quad) ^ l15) * 8));
#pragma unroll
            for (int qt = 0; qt < 4; ++qt)
                o[dt][qt] = __builtin_amdgcn_mfma_f32_16x16x32_bf16(
                    av.b, pb[qt].b, o[dt][qt], 0, 0, 0);
        }
    }

    __syncthreads();
    if (quad == 0) {
#pragma unroll
        for (int qt = 0; qt < 4; ++qt) {
            mlb[(w * 4 + qt) * 16 + l15] = m[qt];
            mlb[256 + (w * 4 + qt) * 16 + l15] = l[qt];
        }
    }
    __syncthreads();
    float scale[4];
#pragma unroll
    for (int qt = 0; qt < 4; ++qt) {
        float M = -__builtin_inff();
#pragma unroll
        for (int ww = 0; ww < 4; ++ww) M = fmaxf(M, mlb[(ww * 4 + qt) * 16 + l15]);
        float L = 0.f;
#pragma unroll
        for (int ww = 0; ww < 4; ++ww)
            L += mlb[256 + (ww * 4 + qt) * 16 + l15] *
                 __expf(mlb[(ww * 4 + qt) * 16 + l15] - M);
        scale[qt] = __expf(m[qt] - M);
        if (w == 0 && quad == 0) lbuf[qt * 16 + l15] = 1.f / L;
    }
    for (int ww = 0; ww < 4; ++ww) {
        if (ww == w) {
#pragma unroll
            for (int qt = 0; qt < 4; ++qt) {
                float* dst = obuf + (qt * 16 + l15) * 72 + quad * 4;
#pragma unroll
                for (int dt = 0; dt < 4; ++dt) {
                    f32x4 v = o[dt][qt] * scale[qt];
                    if (ww != 0) v += *(f32x4*)(dst + dt * 16);
                    *(f32x4*)(dst + dt * 16) = v;
                }
            }
        }
        __syncthreads();
    }
    if (w == 0) {
        float sv = lbuf[lane];
#pragma unroll
        for (int mk = 1; mk < 64; mk <<= 1) sv += __shfl_xor(sv, mk);
        if (lane == 0) atomicAdd(&stats[5], sv);
    }
    {
        const int q = tid >> 2, dseg = (tid & 3) * 16;
        const float il = lbuf[q];
        const float* src = obuf + q * 72 + dseg;
        __align__(16) u16 tmp[16];
#pragma unroll
        for (int j = 0; j < 16; ++j) tmp[j] = f2bf(src[j] * il);
        u16* ydst = y + ((size_t)(b * 1024 + qbase + q)) * 1024 + h * 64 + dseg;
        *(uint4*)(ydst) = *(uint4*)(tmp);
        *(uint4*)(ydst + 8) = *(uint4*)(tmp + 8);
    }
}

// ---------------------------------------------------------------------------
__global__ __launch_bounds__(256)
void finalize_kernel(const int* __restrict__ counts, const float* __restrict__ stats,
                     float* __restrict__ out7) {
    __shared__ float red[4];
    float d = 0.f, z = 0.f, pp = 0.f;
    for (int i = threadIdx.x; i < 4096; i += 256) {
        const int c = counts[i];
        const float frac = (float)c * (1.f / 8192.f);
        d += fabsf(frac - 0.5f);
        z += (c == 0) ? 1.f : 0.f;
        pp += (c == 8192) ? 1.f : 0.f;
    }
    d = block_sum256(d, red);
    z = block_sum256(z, red);
    pp = block_sum256(pp, red);
    if (threadIdx.x == 0) {
        out7[0] = d * (1.f / 4096.f);
        out7[1] = z * (1.f / 4096.f);
        out7[2] = pp * (1.f / 4096.f);
        out7[3] = stats[5] * (1.f / 131072.f);
        out7[4] = sqrtf(stats[0] / stats[1]);
        out7[5] = sqrtf(stats[4] / stats[2]);
        out7[6] = sqrtf(stats[3] / (8192.f * 4096.f));
    }
}

// ---------------------------------------------------------------------------
extern "C" void kernel_launch(void* const* d_in, const int* in_sizes, int n_in,
                              void* d_out, int out_size, void* d_ws, size_t ws_size,
                              hipStream_t stream) {
    const float* x      = (const float*)d_in[0];
    const float* c      = (const float*)d_in[1];
    const float* w_cond = (const float*)d_in[2];
    const float* w_qkv  = (const float*)d_in[3];
    const float* w_attn = (const float*)d_in[4];
    const float* w_mlp1 = (const float*)d_in[5];
    const float* w_mlp2 = (const float*)d_in[6];
    float* out = (float*)d_out;

    char* base = (char*)d_ws;
    size_t off = 0;
    auto alloc = [&](size_t n) { void* r = base + off; off += (n + 255) & ~(size_t)255; return r; };
    float* stats   = (float*)alloc(64);
    int*   counts  = (int*)alloc(4096 * 4);
    float* cm      = (float*)alloc((size_t)8 * 6144 * 4);
    u16*   x_mod   = (u16*)alloc((size_t)8192 * 1024 * 2);
    u16*   kqv     = (u16*)alloc((size_t)8192 * 3072 * 2);
    u16*   vT      = (u16*)alloc((size_t)128 * 64 * 1024 * 2);
    u16*   y       = (u16*)alloc((size_t)8192 * 1024 * 2);
    float* x1      = (float*)alloc((size_t)8192 * 1024 * 4);
    u16*   wt_qkv  = (u16*)alloc((size_t)3072 * 1024 * 2);
    u16*   wt_attn = (u16*)alloc((size_t)1024 * 1024 * 2);
    u16*   wt_mlp1 = (u16*)alloc((size_t)4096 * 1024 * 2);
    u16*   wt_mlp2 = (u16*)alloc((size_t)1024 * 4096 * 2);
    u16*   h_act   = kqv;
    u16*   x_mod2  = x_mod;
    (void)vT; (void)ws_size; (void)n_in; (void)in_sizes; (void)out_size;

    hipMemsetAsync(d_ws, 0, 256 + 4096 * 4, stream);

    dim3 tb(32, 8);
    transpose_cast<<<dim3(3072 / 32, 1024 / 32), tb, 0, stream>>>(w_qkv,  wt_qkv,  1024, 3072);
    transpose_cast<<<dim3(1024 / 32, 1024 / 32), tb, 0, stream>>>(w_attn, wt_attn, 1024, 1024);
    transpose_cast<<<dim3(4096 / 32, 1024 / 32), tb, 0, stream>>>(w_mlp1, wt_mlp1, 1024, 4096);
    transpose_cast<<<dim3(1024 / 32, 4096 / 32), tb, 0, stream>>>(w_mlp2, wt_mlp2, 4096, 1024);

    cond_kernel<<<dim3(24, 8), 256, 0, stream>>>(c, w_cond, cm);

    ln_mod_kernel<<<8192, 256, 0, stream>>>(x, cm, 0, 1024, x_mod);

    // NOTE: grid is (m_tiles, n_tiles) — blockIdx.x = m_tile for XCD locality
    gemm_epi<0><<<dim3(8192 / 128, 3072 / 128), 256, 0, stream>>>(
        x_mod, wt_qkv, 8192, 3072, 1024, kqv, nullptr, nullptr, nullptr, stats, nullptr);

    vtrans_kernel<<<dim3(32, 2, 128), tb, 0, stream>>>(kqv, vT);

    attn_kernel<<<dim3(16, 128), 256, 0, stream>>>(kqv, vT, y, stats);

    gemm_epi<1><<<dim3(8192 / 128, 1024 / 128), 256, 0, stream>>>(
        y, wt_attn, 8192, 1024, 1024, nullptr, x1, x, cm + 2 * 1024, stats, nullptr);

    ln_mod_kernel<<<8192, 256, 0, stream>>>(x1, cm, 3 * 1024, 4 * 1024, x_mod2);

    gemm_epi<2><<<dim3(8192 / 128, 4096 / 128), 256, 0, stream>>>(
        x_mod2, wt_mlp1, 8192, 4096, 1024, h_act, nullptr, nullptr, nullptr, stats, counts);

    gemm_epi<3><<<dim3(8192 / 128, 1024 / 128), 256, 0, stream>>>(
        h_act, wt_mlp2, 8192, 1024, 4096, nullptr, out, x1, cm + 5 * 1024, stats, nullptr);

    finalize_kernel<<<1, 256, 0, stream>>>(counts, stats, out + (size_t)8192 * 1024);
}